// Round 11
// baseline (847.008 us; speedup 1.0000x reference)
//
#include <hip/hip_runtime.h>
#include <hip/hip_bf16.h>

#define N_NODES 10000
#define N_EDGES 40000
#define NLAYERS 5

typedef __bf16 bf16x8 __attribute__((ext_vector_type(8)));
typedef __bf16 bf16x4 __attribute__((ext_vector_type(4)));
typedef float  f32x4  __attribute__((ext_vector_type(4)));

__device__ __forceinline__ bf16x8 cvt8(float4 a, float4 b) {
    bf16x8 r;
    r[0] = (__bf16)a.x; r[1] = (__bf16)a.y; r[2] = (__bf16)a.z; r[3] = (__bf16)a.w;
    r[4] = (__bf16)b.x; r[5] = (__bf16)b.y; r[6] = (__bf16)b.z; r[7] = (__bf16)b.w;
    return r;
}

__device__ __forceinline__ void gload_lds16(const void* g, void* l) {
    __builtin_amdgcn_global_load_lds(
        (const __attribute__((address_space(1))) void*)g,
        (__attribute__((address_space(3))) void*)l, 16, 0, 0);
}

// ---------------- all f32->bf16 weight/x conversions in ONE kernel ----------------
__global__ __launch_bounds__(256) void prep_cvt(
    const float* __restrict__ We, const float* __restrict__ Wq,
    const float* __restrict__ Wk, const float* __restrict__ Wv,
    const float* __restrict__ Wo, const float* __restrict__ mlpW,
    const float* __restrict__ x_in,
    __bf16* __restrict__ wMerged, __bf16* __restrict__ wQKVtmp,
    __bf16* __restrict__ wOd, __bf16* __restrict__ wMd, __bf16* __restrict__ xbb)
{
    const int reg = blockIdx.y;
    long i0 = (long)blockIdx.x * blockDim.x + threadIdx.x;
    long stride = (long)gridDim.x * blockDim.x;
    if (reg == 0) {                       // We -> wMerged rows 0..255 (stride 458752)
        for (long i = i0; i < 81920; i += stride) {
            long e = i * 8; long ch = e >> 16; long r = e & 65535;
            *(bf16x8*)(wMerged + ch * 458752 + r) =
                cvt8(*(const float4*)(We + e), *(const float4*)(We + e + 4));
        }
    } else if (reg == 1 || reg == 2) {    // Wq/Wk row-permuted
        const float* S = (reg == 1) ? Wq : Wk;
        __bf16* D = wQKVtmp + ((reg == 2) ? 131072 : 0);
        for (long i = i0; i < 163840; i += stride) {
            long e = i * 8;
            int slot = (int)(e >> 17); int rem = (int)(e & 131071);
            int row = rem >> 8; int col = rem & 255;
            int srow = ((row & 31) << 4) | (row >> 5);
            const float* sp = S + ((long)slot << 17) + ((long)srow << 8) + col;
            *(bf16x8*)(D + (long)slot * 393216 + ((long)row << 8) + col) =
                cvt8(*(const float4*)sp, *(const float4*)(sp + 4));
        }
    } else if (reg == 3) {                // Wv
        for (long i = i0; i < 163840; i += stride) {
            long e = i * 8; long ch = e >> 17; long r = e & 131071;
            *(bf16x8*)(wQKVtmp + 262144 + ch * 393216 + r) =
                cvt8(*(const float4*)(Wv + e), *(const float4*)(Wv + e + 4));
        }
    } else if (reg == 4) {                // Wo flat
        for (long i = i0; i < 163840; i += stride) {
            long e = i * 8;
            *(bf16x8*)(wOd + e) =
                cvt8(*(const float4*)(Wo + e), *(const float4*)(Wo + e + 4));
        }
    } else if (reg == 5) {                // mlpW flat
        for (long i = i0; i < 40960; i += stride) {
            long e = i * 8;
            *(bf16x8*)(wMd + e) =
                cvt8(*(const float4*)(mlpW + e), *(const float4*)(mlpW + e + 4));
        }
    } else {                              // x_in flat
        for (long i = i0; i < 320000; i += stride) {
            long e = i * 8;
            *(bf16x8*)(xbb + e) =
                cvt8(*(const float4*)(x_in + e), *(const float4*)(x_in + e + 4));
        }
    }
}

// WeT[slot][n][k] = We[slot][k][n], bf16. grid (16, 10).
__global__ __launch_bounds__(256) void transpose_we(
    const float* __restrict__ S, __bf16* __restrict__ D)
{
    __shared__ float tile[64][65];
    const int slot = blockIdx.y;
    const int tx = blockIdx.x & 3, ty = blockIdx.x >> 2;
    const float* sp = S + (size_t)slot * 65536 + (size_t)(ty * 64) * 256 + tx * 64;
    const int t = threadIdx.x;
    #pragma unroll
    for (int j = 0; j < 16; ++j) {
        int idx = t + 256 * j;
        int r = idx >> 6, c = idx & 63;
        tile[r][c] = sp[r * 256 + c];
    }
    __syncthreads();
    __bf16* dp = D + (size_t)slot * 65536 + (size_t)(tx * 64) * 256 + ty * 64;
    #pragma unroll
    for (int j = 0; j < 16; ++j) {
        int idx = t + 256 * j;
        int nl = idx >> 6, kl = idx & 63;
        dp[nl * 256 + kl] = (__bf16)tile[kl][nl];
    }
}

// ---------------- CSR build ----------------
__global__ __launch_bounds__(256) void hist_dst(
    const int* __restrict__ eidx, int* __restrict__ counts)
{
    int e = blockIdx.x * 256 + threadIdx.x;
    if (e < N_EDGES) atomicAdd(&counts[eidx[N_EDGES + e]], 1);
}

__global__ __launch_bounds__(256) void scan_offsets(
    const int* __restrict__ counts, int* __restrict__ offs,
    int* __restrict__ wrk, int n)
{
    const int tid = threadIdx.x;
    const int base = tid * 40;
    int local[40];
    int s = 0;
    #pragma unroll
    for (int j = 0; j < 40; ++j) {
        int i = base + j;
        int v = (i < n) ? counts[i] : 0;
        local[j] = s; s += v;
    }
    __shared__ int sm[256];
    sm[tid] = s;
    __syncthreads();
    for (int off = 1; off < 256; off <<= 1) {
        int t2 = (tid >= off) ? sm[tid - off] : 0;
        __syncthreads();
        sm[tid] += t2;
        __syncthreads();
    }
    int pre = (tid == 0) ? 0 : sm[tid - 1];
    #pragma unroll
    for (int j = 0; j < 40; ++j) {
        int i = base + j;
        if (i < n) { int v = pre + local[j]; offs[i] = v; wrk[i] = v; }
    }
    if (tid == 255) offs[n] = sm[255];
}

__global__ __launch_bounds__(256) void scatter_csr(
    const int* __restrict__ eidx, int* __restrict__ wrk, int* __restrict__ csr_src)
{
    int e = blockIdx.x * 256 + threadIdx.x;
    if (e < N_EDGES) {
        int sn = eidx[e];
        int d  = eidx[N_EDGES + e];
        int pos = atomicAdd(&wrk[d], 1);
        csr_src[pos] = sn;
    }
}

// ---------------- LDS-staged bf16 GEMM (merged x->xe|QKV + weight prep) ----------------
template<int MODE, int BN>
__global__ __launch_bounds__(256) void gemm_lds(
    const __bf16* __restrict__ A, const __bf16* __restrict__ W,
    float* __restrict__ Cf, __bf16* __restrict__ Ch,
    int M, int K, int ldc, long sA, long sW, long sC)
{
    __shared__ __bf16 As[128 * 64];
    __shared__ __bf16 Wsh[BN * 64];
    constexpr int NF = BN / 32;
    A += (long)blockIdx.z * sA;
    W += (long)blockIdx.z * sW;
    if (Ch) Ch += (long)blockIdx.z * sC;
    const int tid = threadIdx.x;
    const int ln  = tid & 63;
    const int wv  = tid >> 6;
    const int wr  = wv >> 1, wc = wv & 1;
    const int brow0 = blockIdx.y * 128;
    const int colb0 = blockIdx.x * BN;

    const int srow = ln >> 3;
    const int scol = ((ln & 7) ^ srow) * 8;
    const int fr = ln & 15;
    const int kq = ln >> 4;
    char* asb = (char*)As;
    char* wsb = (char*)Wsh;

    f32x4 acc[4][NF];
    #pragma unroll
    for (int m = 0; m < 4; ++m)
        #pragma unroll
        for (int n = 0; n < NF; ++n) acc[m][n] = (f32x4){0.f, 0.f, 0.f, 0.f};

    const int nt = K >> 6;
    for (int t = 0; t < nt; ++t) {
        const int kk0 = t << 6;
        if (t) __syncthreads();
        #pragma unroll
        for (int c = 0; c < 4; ++c) {
            int ch = wv * 4 + c;
            int grow = brow0 + ch * 8 + srow;
            if (grow >= M) grow = M - 1;
            gload_lds16(A + (size_t)grow * K + kk0 + scol, asb + ch * 1024);
        }
        #pragma unroll
        for (int c = 0; c < NF; ++c) {
            int ch = wv * NF + c;
            int grow = colb0 + ch * 8 + srow;
            gload_lds16(W + (size_t)grow * K + kk0 + scol, wsb + ch * 1024);
        }
        __syncthreads();
        #pragma unroll
        for (int ks = 0; ks < 2; ++ks) {
            const int kb = ks * 64 + kq * 16;
            const int sw = (fr & 7) << 4;
            bf16x8 af[4], wf[NF];
            #pragma unroll
            for (int m = 0; m < 4; ++m) {
                int row = wr * 64 + m * 16 + fr;
                af[m] = *(const bf16x8*)(asb + row * 128 + (kb ^ sw));
            }
            #pragma unroll
            for (int n = 0; n < NF; ++n) {
                int row = wc * (BN / 2) + n * 16 + fr;
                wf[n] = *(const bf16x8*)(wsb + row * 128 + (kb ^ sw));
            }
            #pragma unroll
            for (int m = 0; m < 4; ++m)
                #pragma unroll
                for (int n = 0; n < NF; ++n)
                    acc[m][n] = __builtin_amdgcn_mfma_f32_16x16x32_bf16(
                        af[m], wf[n], acc[m][n], 0, 0, 0);
        }
    }

    const int rq = (ln >> 4) * 4;
    #pragma unroll
    for (int m = 0; m < 4; ++m) {
        #pragma unroll
        for (int rr = 0; rr < 4; ++rr) {
            int orow = brow0 + wr * 64 + m * 16 + rq + rr;
            if (orow < M) {
                #pragma unroll
                for (int n = 0; n < NF; ++n) {
                    int c = colb0 + wc * (BN / 2) + fr + n * 16;
                    if (MODE == 0)      Cf[(size_t)orow * ldc + c] = acc[m][n][rr];
                    else if (MODE == 1) Ch[(size_t)orow * ldc + c] = (__bf16)acc[m][n][rr];
                    else {
                        if (c < 256) Ch[(size_t)orow * 256 + c] = (__bf16)acc[m][n][rr];
                        else ((__bf16*)Cf)[(size_t)orow * 1536 + (c - 256)] = (__bf16)acc[m][n][rr];
                    }
                }
            }
        }
    }
}

// ---------------- per-dst attention via MFMA, one wave per node ----------------
// qkv per node (1536 bf16): Q^T[16a][32h] | K^T[16a][32h] | V[32h][16b].
__global__ __launch_bounds__(256) void edge_attn_csr(
    const int* __restrict__ csr_off, const int* __restrict__ csr_src,
    const __bf16* __restrict__ qkv, __bf16* __restrict__ attn_bf)
{
    const int lane = threadIdx.x & 63;
    const int d = blockIdx.x * 4 + (threadIdx.x >> 6);
    const int fr = lane & 15;
    const int G  = lane >> 4;

    const __bf16* qT = qkv + (size_t)d * 1536;
    const bf16x8 qf = *(const bf16x8*)(qT + fr * 32 + G * 8);

    const f32x4 zero = {0.f, 0.f, 0.f, 0.f};
    f32x4 acc0 = zero, acc1 = zero;

    const int i0 = csr_off[d], i1 = csr_off[d + 1];
    int sN = (i0 < i1) ? csr_src[i0] : 0;
    bf16x8 kfN = *(const bf16x8*)(qkv + (size_t)sN * 1536 + 512 + fr * 32 + G * 8);
    for (int i = i0; i < i1; ++i) {
        const int s = sN;
        const bf16x8 kf = kfN;
        if (i + 1 < i1) {
            sN = csr_src[i + 1];
            kfN = *(const bf16x8*)(qkv + (size_t)sN * 1536 + 512 + fr * 32 + G * 8);
        }
        const __bf16* vp = qkv + (size_t)s * 1536 + 1024;
        bf16x8 vf0 = {0, 0, 0, 0, 0, 0, 0, 0};
        bf16x8 vf1 = {0, 0, 0, 0, 0, 0, 0, 0};
        if (G < 2) {
            vf0 = *(const bf16x8*)(vp + fr * 16 + G * 8);
            vf1 = *(const bf16x8*)(vp + (16 + fr) * 16 + G * 8);
        }
        f32x4 al = __builtin_amdgcn_mfma_f32_16x16x32_bf16(kf, qf, zero, 0, 0, 0);

        float mx = fmaxf(fmaxf(al[0], al[1]), fmaxf(al[2], al[3]));
        mx = fmaxf(mx, __shfl_xor(mx, 16));
        mx = fmaxf(mx, __shfl_xor(mx, 32));
        float p[4];
        #pragma unroll
        for (int r = 0; r < 4; ++r) p[r] = __expf((al[r] - mx) * 0.25f);
        float sum = p[0] + p[1] + p[2] + p[3];
        sum += __shfl_xor(sum, 16);
        sum += __shfl_xor(sum, 32);
        const float inv = 1.f / sum;

        bf16x8 paf;
        #pragma unroll
        for (int j = 0; j < 8; ++j) {
            int srcLane = fr + ((G * 8 + j) >> 2) * 16;
            float v = __shfl(p[j & 3], srcLane);
            paf[j] = (G < 2) ? (__bf16)(v * inv) : (__bf16)0.f;
        }

        acc0 = __builtin_amdgcn_mfma_f32_16x16x32_bf16(paf, vf0, acc0, 0, 0, 0);
        acc1 = __builtin_amdgcn_mfma_f32_16x16x32_bf16(paf, vf1, acc1, 0, 0, 0);
    }

    __bf16* ob = attn_bf + (size_t)d * 512;
    bf16x4 o0, o1;
    #pragma unroll
    for (int r = 0; r < 4; ++r) { o0[r] = (__bf16)acc0[r]; o1[r] = (__bf16)acc1[r]; }
    *(bf16x4*)(ob + fr * 16 + G * 4)       = o0;
    *(bf16x4*)(ob + 256 + fr * 16 + G * 4) = o1;
}

// ---------------- fused Wo-GEMM + residual + LN (+ optional chained MLP+LN) ----------------
// 512 threads (8 waves), BM=16 rows; wave wv owns cols [wv*32, wv*32+32).
// A staged ONCE into tile-major LDS [8 tiles][16 rows][128B] (2-way-max bank
// pattern); W read from global (L2-resident). grid 625.
template<bool CHAIN>
__global__ __launch_bounds__(512) void fused_tail(
    const __bf16* __restrict__ A, const __bf16* __restrict__ W,
    const __bf16* __restrict__ xres, const __bf16* __restrict__ tb,
    const float* __restrict__ bias, const float* __restrict__ g1,
    const float* __restrict__ b1,
    const __bf16* __restrict__ Wm, const float* __restrict__ mb,
    const float* __restrict__ g2, const float* __restrict__ b2,
    float* __restrict__ outf, __bf16* __restrict__ outb, int M)
{
    __shared__ __bf16 As[16 * 512];                // 16 KB: [8][16 rows][128 B]
    __shared__ __bf16 X1[CHAIN ? 16 * 256 : 8];    // 8 KB: [4][16 rows][128 B]
    __shared__ float sm_s[8][16];
    __shared__ float sm_q[8][16];
    const int tid = threadIdx.x;
    const int ln  = tid & 63;
    const int wv  = tid >> 6;      // 0..7
    const int fr  = ln & 15;
    const int kq  = ln >> 4;
    const int brow0 = blockIdx.x * 16;
    char* asb = (char*)As;
    char* x1b = (char*)X1;
    const f32x4 zero = {0.f, 0.f, 0.f, 0.f};
    const int sw = (fr & 7) << 4;
    const int colw = wv * 32;

    // ---- stage A once: 16 chunks (tile t = ch>>1, rows (ch&1)*8..+8), swz src ----
    #pragma unroll
    for (int c = 0; c < 2; ++c) {
        int ch = wv * 2 + c;
        int t  = ch >> 1;
        int r  = (ch & 1) * 8 + (ln >> 3);
        int grow = brow0 + r; if (grow >= M) grow = M - 1;
        int slot = (ln & 7) ^ (r & 7);
        gload_lds16((const char*)A + (size_t)grow * 1024 + t * 128 + slot * 16,
                    asb + ch * 1024);
    }
    __syncthreads();

    // ---- phase 1: K=512 GEMM, barrier-free; W from global ----
    f32x4 acc[2];
    acc[0] = zero; acc[1] = zero;
    #pragma unroll
    for (int t = 0; t < 8; ++t) {
        #pragma unroll
        for (int ks = 0; ks < 2; ++ks) {
            const int kb = ks * 64 + kq * 16;
            bf16x8 af = *(const bf16x8*)(asb + t * 2048 + fr * 128 + (kb ^ sw));
            const __bf16* wp = W + (size_t)(colw + fr) * 512 + t * 64 + ks * 32 + kq * 8;
            bf16x8 wf0 = *(const bf16x8*)wp;
            bf16x8 wf1 = *(const bf16x8*)(wp + 16 * 512);
            acc[0] = __builtin_amdgcn_mfma_f32_16x16x32_bf16(af, wf0, acc[0], 0, 0, 0);
            acc[1] = __builtin_amdgcn_mfma_f32_16x16x32_bf16(af, wf1, acc[1], 0, 0, 0);
        }
    }

    // ---- residual + LN1 stats ----
    float s2[4] = {0, 0, 0, 0}, q2[4] = {0, 0, 0, 0};
    #pragma unroll
    for (int n = 0; n < 2; ++n) {
        const int col = colw + n * 16 + fr;
        const float bi = bias[col];
        #pragma unroll
        for (int rr = 0; rr < 4; ++rr) {
            int gr = brow0 + kq * 4 + rr; if (gr >= M) gr = M - 1;
            float v = acc[n][rr] + (float)xres[(size_t)gr * 256 + col]
                      + (float)tb[(size_t)gr * 256 + col] + bi;
            acc[n][rr] = v;
            s2[rr] += v; q2[rr] += v * v;
        }
    }
    #pragma unroll
    for (int mask = 1; mask < 16; mask <<= 1)
        #pragma unroll
        for (int rr = 0; rr < 4; ++rr) {
            s2[rr] += __shfl_xor(s2[rr], mask);
            q2[rr] += __shfl_xor(q2[rr], mask);
        }
    if (fr == 0) {
        #pragma unroll
        for (int rr = 0; rr < 4; ++rr) {
            sm_s[wv][kq * 4 + rr] = s2[rr];
            sm_q[wv][kq * 4 + rr] = q2[rr];
        }
    }
    __syncthreads();
    float mean[4], invs[4];
    #pragma unroll
    for (int rr = 0; rr < 4; ++rr) {
        int rw = kq * 4 + rr;
        float ts = 0.f, tq = 0.f;
        #pragma unroll
        for (int w = 0; w < 8; ++w) { ts += sm_s[w][rw]; tq += sm_q[w][rw]; }
        float mn = ts * (1.f / 256.f);
        mean[rr] = mn;
        invs[rr] = rsqrtf(tq * (1.f / 256.f) - mn * mn + 1e-5f);
    }

    if (!CHAIN) {
        #pragma unroll
        for (int n = 0; n < 2; ++n) {
            const int col = colw + n * 16 + fr;
            const float gv = g1[col], bv = b1[col];
            #pragma unroll
            for (int rr = 0; rr < 4; ++rr) {
                int gr = brow0 + kq * 4 + rr;
                if (gr < M) {
                    float o = (acc[n][rr] - mean[rr]) * invs[rr] * gv + bv;
                    outb[(size_t)gr * 256 + col] = (__bf16)o;
                    if (outf) outf[(size_t)gr * 256 + col] = o;
                }
            }
        }
        return;
    }

    // ---- chained MLP: x1 -> tile-major swizzled LDS; x2 = LN(x1 + x1@Wm^T + mb) ----
    #pragma unroll
    for (int n = 0; n < 2; ++n) {
        const int col = colw + n * 16 + fr;
        const int tx = col >> 6, c64 = col & 63;
        const float gv = g1[col], bv = b1[col];
        #pragma unroll
        for (int rr = 0; rr < 4; ++rr) {
            int row = kq * 4 + rr;
            float o = (acc[n][rr] - mean[rr]) * invs[rr] * gv + bv;
            *(__bf16*)(x1b + tx * 2048 + row * 128 + ((c64 * 2) ^ ((row & 7) << 4))) = (__bf16)o;
        }
    }
    __syncthreads();

    f32x4 acc2[2];
    acc2[0] = zero; acc2[1] = zero;
    #pragma unroll
    for (int t = 0; t < 4; ++t) {
        #pragma unroll
        for (int ks = 0; ks < 2; ++ks) {
            const int kb = ks * 64 + kq * 16;
            bf16x8 af = *(const bf16x8*)(x1b + t * 2048 + fr * 128 + (kb ^ sw));
            const __bf16* wp = Wm + (size_t)(colw + fr) * 256 + t * 64 + ks * 32 + kq * 8;
            bf16x8 wf0 = *(const bf16x8*)wp;
            bf16x8 wf1 = *(const bf16x8*)(wp + 16 * 256);
            acc2[0] = __builtin_amdgcn_mfma_f32_16x16x32_bf16(af, wf0, acc2[0], 0, 0, 0);
            acc2[1] = __builtin_amdgcn_mfma_f32_16x16x32_bf16(af, wf1, acc2[1], 0, 0, 0);
        }
    }

    float s3[4] = {0, 0, 0, 0}, q3[4] = {0, 0, 0, 0};
    #pragma unroll
    for (int n = 0; n < 2; ++n) {
        const int col = colw + n * 16 + fr;
        const int tx = col >> 6, c64 = col & 63;
        const float bi = mb[col];
        #pragma unroll
        for (int rr = 0; rr < 4; ++rr) {
            int row = kq * 4 + rr;
            float x1v = (float)*(const __bf16*)(
                x1b + tx * 2048 + row * 128 + ((c64 * 2) ^ ((row & 7) << 4)));
            float v = acc2[n][rr] + x1v + bi;
            acc2[n][rr] = v;
            s3[rr] += v; q3[rr] += v * v;
        }
    }
    #pragma unroll
    for (int mask = 1; mask < 16; mask <<= 1)
        #pragma unroll
        for (int rr = 0; rr < 4; ++rr) {
            s3[rr] += __shfl_xor(s3[rr], mask);
            q3[rr] += __shfl_xor(q3[rr], mask);
        }
    __syncthreads();   // all LN1 sm reads done before overwrite
    if (fr == 0) {
        #pragma unroll
        for (int rr = 0; rr < 4; ++rr) {
            sm_s[wv][kq * 4 + rr] = s3[rr];
            sm_q[wv][kq * 4 + rr] = q3[rr];
        }
    }
    __syncthreads();
    #pragma unroll
    for (int rr = 0; rr < 4; ++rr) {
        int rw = kq * 4 + rr;
        float ts = 0.f, tq = 0.f;
        #pragma unroll
        for (int w = 0; w < 8; ++w) { ts += sm_s[w][rw]; tq += sm_q[w][rw]; }
        float mn = ts * (1.f / 256.f);
        mean[rr] = mn;
        invs[rr] = rsqrtf(tq * (1.f / 256.f) - mn * mn + 1e-5f);
    }
    #pragma unroll
    for (int n = 0; n < 2; ++n) {
        const int col = colw + n * 16 + fr;
        const float gv = g2[col], bv = b2[col];
        #pragma unroll
        for (int rr = 0; rr < 4; ++rr) {
            int gr = brow0 + kq * 4 + rr;
            if (gr < M) {
                float o = (acc2[n][rr] - mean[rr]) * invs[rr] * gv + bv;
                outb[(size_t)gr * 256 + col] = (__bf16)o;
                if (outf) outf[(size_t)gr * 256 + col] = o;
            }
        }
    }
}

extern "C" void kernel_launch(void* const* d_in, const int* in_sizes, int n_in,
                              void* d_out, int out_size, void* d_ws, size_t ws_size,
                              hipStream_t stream)
{
    const int*   eidx = (const int*)  d_in[0];
    const float* x_in = (const float*)d_in[1];
    const float* We   = (const float*)d_in[2];
    const float* Wq   = (const float*)d_in[3];
    const float* Wk   = (const float*)d_in[4];
    const float* Wv   = (const float*)d_in[5];
    const float* Wo   = (const float*)d_in[6];
    const float* bo   = (const float*)d_in[7];
    const float* lng  = (const float*)d_in[8];
    const float* lnb  = (const float*)d_in[9];
    const float* mlpW = (const float*)d_in[10];
    const float* mlpb = (const float*)d_in[11];
    float* out = (float*)d_out;

    char* p = (char*)d_ws;
    __bf16* wMerged = (__bf16*)p; p += (size_t)10 * 458752 * 2;  // [10][1792][256]
    __bf16* wQKVtmp = (__bf16*)p; p += (size_t)10 * 393216 * 2;
    __bf16* wET     = (__bf16*)p; p += (size_t)10 * 65536  * 2;
    __bf16* wO      = (__bf16*)p; p += (size_t)10 * 131072 * 2;
    __bf16* wM      = (__bf16*)p; p += (size_t)5  * 65536  * 2;
    __bf16* qkv     = (__bf16*)p; p += (size_t)N_NODES * 1536 * 2;
    __bf16* attn_bf = (__bf16*)p; p += (size_t)N_NODES * 512 * 2;
    __bf16* xeb     = (__bf16*)p; p += (size_t)N_NODES * 256 * 2;
    __bf16* xbb     = (__bf16*)p; p += (size_t)N_NODES * 256 * 2;
    int* counts  = (int*)p;    p += (size_t)(N_NODES + 16) * 4;
    int* csr_off = (int*)p;    p += (size_t)(N_NODES + 16) * 4;
    int* csr_wrk = (int*)p;    p += (size_t)(N_NODES + 16) * 4;
    int* csr_src = (int*)p;    p += (size_t)N_EDGES * 4;
    if ((size_t)(p - (char*)d_ws) > ws_size) return;

    dim3 blk(256);

    // ---- prep: CSR + weight conversion ----
    hipMemsetAsync(counts, 0, (size_t)(N_NODES + 16) * 4, stream);
    hist_dst<<<dim3(157), blk, 0, stream>>>(eidx, counts);
    scan_offsets<<<dim3(1), blk, 0, stream>>>(counts, csr_off, csr_wrk, N_NODES);
    scatter_csr<<<dim3(157), blk, 0, stream>>>(eidx, csr_wrk, csr_src);

    prep_cvt<<<dim3(128, 7), blk, 0, stream>>>(We, Wq, Wk, Wv, Wo, mlpW, x_in,
                                               wMerged, wQKVtmp, wO, wM, xbb);
    transpose_we<<<dim3(16, 10), blk, 0, stream>>>(We, wET);

    // W'[l] = Wqkv_perm[l] @ We[l] -> wMerged rows 256..1791 (batched)
    gemm_lds<1, 64><<<dim3(4, 12, 10), blk, 0, stream>>>(
        wQKVtmp, wET, nullptr, wMerged + 65536, 1536, 256, 256,
        393216, 65536, 458752);

    dim3 gMerged(14, 79);   // BN=128, Nc=1792

    for (int l = 0; l < NLAYERS; ++l) {
        for (int s = 0; s < 2; ++s) {
            size_t ls = (size_t)(l * 2 + s);
            // xe | Q^T|K^T|V = x @ [We; Wqkv@We]^T  (one GEMM)
            gemm_lds<3, 128><<<gMerged, blk, 0, stream>>>(
                xbb, wMerged + ls * 458752, (float*)qkv, xeb, N_NODES, 256, 0, 0, 0, 0);
            edge_attn_csr<<<dim3(N_NODES / 4), blk, 0, stream>>>(csr_off, csr_src,
                                                                 qkv, attn_bf);
            if (s == 0) {
                fused_tail<false><<<dim3(625), dim3(512), 0, stream>>>(
                    attn_bf, wO + ls * 131072, xbb, xeb, bo + ls * 256,
                    lng + (size_t)(l * 3) * 256, lnb + (size_t)(l * 3) * 256,
                    nullptr, nullptr, nullptr, nullptr,
                    nullptr, xbb, N_NODES);
            } else {
                bool lastL = (l == NLAYERS - 1);
                fused_tail<true><<<dim3(625), dim3(512), 0, stream>>>(
                    attn_bf, wO + ls * 131072, xbb, xeb, bo + ls * 256,
                    lng + (size_t)(l * 3 + 1) * 256, lnb + (size_t)(l * 3 + 1) * 256,
                    wM + (size_t)l * 65536, mlpb + (size_t)l * 256,
                    lng + (size_t)(l * 3 + 2) * 256, lnb + (size_t)(l * 3 + 2) * 256,
                    lastL ? out : nullptr, xbb, N_NODES);
            }
        }
    }
}

// Round 13
// 658.482 us; speedup vs baseline: 1.2863x; 1.2863x over previous
//
#include <hip/hip_runtime.h>
#include <hip/hip_bf16.h>

#define N_NODES 10000
#define N_EDGES 40000
#define NLAYERS 5

typedef __bf16 bf16x8 __attribute__((ext_vector_type(8)));
typedef __bf16 bf16x4 __attribute__((ext_vector_type(4)));
typedef float  f32x4  __attribute__((ext_vector_type(4)));

__device__ __forceinline__ bf16x8 cvt8(float4 a, float4 b) {
    bf16x8 r;
    r[0] = (__bf16)a.x; r[1] = (__bf16)a.y; r[2] = (__bf16)a.z; r[3] = (__bf16)a.w;
    r[4] = (__bf16)b.x; r[5] = (__bf16)b.y; r[6] = (__bf16)b.z; r[7] = (__bf16)b.w;
    return r;
}

__device__ __forceinline__ void gload_lds16(const void* g, void* l) {
    __builtin_amdgcn_global_load_lds(
        (const __attribute__((address_space(1))) void*)g,
        (__attribute__((address_space(3))) void*)l, 16, 0, 0);
}

// T1: bijective XCD-aware block swizzle (m204). Permutes flat block index so
// each of the 8 XCDs gets a contiguous chunk. Pure relabeling — correctness-safe.
__device__ __forceinline__ int xcd_swz(int flat, int nwg) {
    int xcd = flat & 7;
    int idx = flat >> 3;
    int q = nwg >> 3, r = nwg & 7;
    return (xcd < r ? xcd * (q + 1) : r * (q + 1) + (xcd - r) * q) + idx;
}

// ---------------- all f32->bf16 weight/x conversions in ONE kernel ----------------
__global__ __launch_bounds__(256) void prep_cvt(
    const float* __restrict__ We, const float* __restrict__ Wq,
    const float* __restrict__ Wk, const float* __restrict__ Wv,
    const float* __restrict__ Wo, const float* __restrict__ mlpW,
    const float* __restrict__ x_in,
    __bf16* __restrict__ wMerged, __bf16* __restrict__ wQKVtmp,
    __bf16* __restrict__ wOd, __bf16* __restrict__ wMd, __bf16* __restrict__ xbb)
{
    const int reg = blockIdx.y;
    long i0 = (long)blockIdx.x * blockDim.x + threadIdx.x;
    long stride = (long)gridDim.x * blockDim.x;
    if (reg == 0) {                       // We -> wMerged rows 0..255 (stride 458752)
        for (long i = i0; i < 81920; i += stride) {
            long e = i * 8; long ch = e >> 16; long r = e & 65535;
            *(bf16x8*)(wMerged + ch * 458752 + r) =
                cvt8(*(const float4*)(We + e), *(const float4*)(We + e + 4));
        }
    } else if (reg == 1 || reg == 2) {    // Wq/Wk row-permuted
        const float* S = (reg == 1) ? Wq : Wk;
        __bf16* D = wQKVtmp + ((reg == 2) ? 131072 : 0);
        for (long i = i0; i < 163840; i += stride) {
            long e = i * 8;
            int slot = (int)(e >> 17); int rem = (int)(e & 131071);
            int row = rem >> 8; int col = rem & 255;
            int srow = ((row & 31) << 4) | (row >> 5);
            const float* sp = S + ((long)slot << 17) + ((long)srow << 8) + col;
            *(bf16x8*)(D + (long)slot * 393216 + ((long)row << 8) + col) =
                cvt8(*(const float4*)sp, *(const float4*)(sp + 4));
        }
    } else if (reg == 3) {                // Wv
        for (long i = i0; i < 163840; i += stride) {
            long e = i * 8; long ch = e >> 17; long r = e & 131071;
            *(bf16x8*)(wQKVtmp + 262144 + ch * 393216 + r) =
                cvt8(*(const float4*)(Wv + e), *(const float4*)(Wv + e + 4));
        }
    } else if (reg == 4) {                // Wo flat
        for (long i = i0; i < 163840; i += stride) {
            long e = i * 8;
            *(bf16x8*)(wOd + e) =
                cvt8(*(const float4*)(Wo + e), *(const float4*)(Wo + e + 4));
        }
    } else if (reg == 5) {                // mlpW flat
        for (long i = i0; i < 40960; i += stride) {
            long e = i * 8;
            *(bf16x8*)(wMd + e) =
                cvt8(*(const float4*)(mlpW + e), *(const float4*)(mlpW + e + 4));
        }
    } else {                              // x_in flat
        for (long i = i0; i < 320000; i += stride) {
            long e = i * 8;
            *(bf16x8*)(xbb + e) =
                cvt8(*(const float4*)(x_in + e), *(const float4*)(x_in + e + 4));
        }
    }
}

// WeT[slot][n][k] = We[slot][k][n], bf16. grid (16, 10).
__global__ __launch_bounds__(256) void transpose_we(
    const float* __restrict__ S, __bf16* __restrict__ D)
{
    __shared__ float tile[64][65];
    const int slot = blockIdx.y;
    const int tx = blockIdx.x & 3, ty = blockIdx.x >> 2;
    const float* sp = S + (size_t)slot * 65536 + (size_t)(ty * 64) * 256 + tx * 64;
    const int t = threadIdx.x;
    #pragma unroll
    for (int j = 0; j < 16; ++j) {
        int idx = t + 256 * j;
        int r = idx >> 6, c = idx & 63;
        tile[r][c] = sp[r * 256 + c];
    }
    __syncthreads();
    __bf16* dp = D + (size_t)slot * 65536 + (size_t)(tx * 64) * 256 + ty * 64;
    #pragma unroll
    for (int j = 0; j < 16; ++j) {
        int idx = t + 256 * j;
        int nl = idx >> 6, kl = idx & 63;
        dp[nl * 256 + kl] = (__bf16)tile[kl][nl];
    }
}

// ---------------- CSR build ----------------
__global__ __launch_bounds__(256) void hist_dst(
    const int* __restrict__ eidx, int* __restrict__ counts)
{
    int e = blockIdx.x * 256 + threadIdx.x;
    if (e < N_EDGES) atomicAdd(&counts[eidx[N_EDGES + e]], 1);
}

__global__ __launch_bounds__(256) void scan_offsets(
    const int* __restrict__ counts, int* __restrict__ offs,
    int* __restrict__ wrk, int n)
{
    const int tid = threadIdx.x;
    const int base = tid * 40;
    int local[40];
    int s = 0;
    #pragma unroll
    for (int j = 0; j < 40; ++j) {
        int i = base + j;
        int v = (i < n) ? counts[i] : 0;
        local[j] = s; s += v;
    }
    __shared__ int sm[256];
    sm[tid] = s;
    __syncthreads();
    for (int off = 1; off < 256; off <<= 1) {
        int t2 = (tid >= off) ? sm[tid - off] : 0;
        __syncthreads();
        sm[tid] += t2;
        __syncthreads();
    }
    int pre = (tid == 0) ? 0 : sm[tid - 1];
    #pragma unroll
    for (int j = 0; j < 40; ++j) {
        int i = base + j;
        if (i < n) { int v = pre + local[j]; offs[i] = v; wrk[i] = v; }
    }
    if (tid == 255) offs[n] = sm[255];
}

__global__ __launch_bounds__(256) void scatter_csr(
    const int* __restrict__ eidx, int* __restrict__ wrk, int* __restrict__ csr_src)
{
    int e = blockIdx.x * 256 + threadIdx.x;
    if (e < N_EDGES) {
        int sn = eidx[e];
        int d  = eidx[N_EDGES + e];
        int pos = atomicAdd(&wrk[d], 1);
        csr_src[pos] = sn;
    }
}

// ---------------- LDS-staged bf16 GEMM (merged x->xe|QKV + weight prep) ----------------
template<int MODE, int BN>
__global__ __launch_bounds__(256) void gemm_lds(
    const __bf16* __restrict__ A, const __bf16* __restrict__ W,
    float* __restrict__ Cf, __bf16* __restrict__ Ch,
    int M, int K, int ldc, long sA, long sW, long sC)
{
    __shared__ __bf16 As[128 * 64];
    __shared__ __bf16 Wsh[BN * 64];
    constexpr int NF = BN / 32;
    A += (long)blockIdx.z * sA;
    W += (long)blockIdx.z * sW;
    if (Ch) Ch += (long)blockIdx.z * sC;
    const int tid = threadIdx.x;
    const int ln  = tid & 63;
    const int wv  = tid >> 6;
    const int wr  = wv >> 1, wc = wv & 1;

    // T1 XCD swizzle of the (x,y) block coordinates (bijective, perf-only)
    const int nx = gridDim.x, nwg = nx * gridDim.y;
    const int swz = xcd_swz(blockIdx.y * nx + blockIdx.x, nwg);
    const int brow0 = (swz / nx) * 128;
    const int colb0 = (swz % nx) * BN;

    const int srow = ln >> 3;
    const int scol = ((ln & 7) ^ srow) * 8;
    const int fr = ln & 15;
    const int kq = ln >> 4;
    char* asb = (char*)As;
    char* wsb = (char*)Wsh;

    f32x4 acc[4][NF];
    #pragma unroll
    for (int m = 0; m < 4; ++m)
        #pragma unroll
        for (int n = 0; n < NF; ++n) acc[m][n] = (f32x4){0.f, 0.f, 0.f, 0.f};

    const int nt = K >> 6;
    for (int t = 0; t < nt; ++t) {
        const int kk0 = t << 6;
        if (t) __syncthreads();
        #pragma unroll
        for (int c = 0; c < 4; ++c) {
            int ch = wv * 4 + c;
            int grow = brow0 + ch * 8 + srow;
            if (grow >= M) grow = M - 1;
            gload_lds16(A + (size_t)grow * K + kk0 + scol, asb + ch * 1024);
        }
        #pragma unroll
        for (int c = 0; c < NF; ++c) {
            int ch = wv * NF + c;
            int grow = colb0 + ch * 8 + srow;
            gload_lds16(W + (size_t)grow * K + kk0 + scol, wsb + ch * 1024);
        }
        __syncthreads();
        #pragma unroll
        for (int ks = 0; ks < 2; ++ks) {
            const int kb = ks * 64 + kq * 16;
            const int sw = (fr & 7) << 4;
            bf16x8 af[4], wf[NF];
            #pragma unroll
            for (int m = 0; m < 4; ++m) {
                int row = wr * 64 + m * 16 + fr;
                af[m] = *(const bf16x8*)(asb + row * 128 + (kb ^ sw));
            }
            #pragma unroll
            for (int n = 0; n < NF; ++n) {
                int row = wc * (BN / 2) + n * 16 + fr;
                wf[n] = *(const bf16x8*)(wsb + row * 128 + (kb ^ sw));
            }
            #pragma unroll
            for (int m = 0; m < 4; ++m)
                #pragma unroll
                for (int n = 0; n < NF; ++n)
                    acc[m][n] = __builtin_amdgcn_mfma_f32_16x16x32_bf16(
                        af[m], wf[n], acc[m][n], 0, 0, 0);
        }
    }

    const int rq = (ln >> 4) * 4;
    #pragma unroll
    for (int m = 0; m < 4; ++m) {
        #pragma unroll
        for (int rr = 0; rr < 4; ++rr) {
            int orow = brow0 + wr * 64 + m * 16 + rq + rr;
            if (orow < M) {
                #pragma unroll
                for (int n = 0; n < NF; ++n) {
                    int c = colb0 + wc * (BN / 2) + fr + n * 16;
                    if (MODE == 0)      Cf[(size_t)orow * ldc + c] = acc[m][n][rr];
                    else if (MODE == 1) Ch[(size_t)orow * ldc + c] = (__bf16)acc[m][n][rr];
                    else {
                        if (c < 256) Ch[(size_t)orow * 256 + c] = (__bf16)acc[m][n][rr];
                        else ((__bf16*)Cf)[(size_t)orow * 1536 + (c - 256)] = (__bf16)acc[m][n][rr];
                    }
                }
            }
        }
    }
}

// ---------------- per-dst attention via MFMA, one wave per node ----------------
// qkv per node (1536 bf16): Q^T[16a][32h] | K^T[16a][32h] | V[32h][16b].
__global__ __launch_bounds__(256) void edge_attn_csr(
    const int* __restrict__ csr_off, const int* __restrict__ csr_src,
    const __bf16* __restrict__ qkv, __bf16* __restrict__ attn_bf)
{
    const int lane = threadIdx.x & 63;
    const int blk = xcd_swz(blockIdx.x, gridDim.x);   // T1: contiguous nodes/XCD
    const int d = blk * 4 + (threadIdx.x >> 6);
    const int fr = lane & 15;
    const int G  = lane >> 4;

    const __bf16* qT = qkv + (size_t)d * 1536;
    const bf16x8 qf = *(const bf16x8*)(qT + fr * 32 + G * 8);

    const f32x4 zero = {0.f, 0.f, 0.f, 0.f};
    f32x4 acc0 = zero, acc1 = zero;

    const int i0 = csr_off[d], i1 = csr_off[d + 1];
    int sN = (i0 < i1) ? csr_src[i0] : 0;
    bf16x8 kfN = *(const bf16x8*)(qkv + (size_t)sN * 1536 + 512 + fr * 32 + G * 8);
    for (int i = i0; i < i1; ++i) {
        const int s = sN;
        const bf16x8 kf = kfN;
        if (i + 1 < i1) {
            sN = csr_src[i + 1];
            kfN = *(const bf16x8*)(qkv + (size_t)sN * 1536 + 512 + fr * 32 + G * 8);
        }
        const __bf16* vp = qkv + (size_t)s * 1536 + 1024;
        bf16x8 vf0 = {0, 0, 0, 0, 0, 0, 0, 0};
        bf16x8 vf1 = {0, 0, 0, 0, 0, 0, 0, 0};
        if (G < 2) {
            vf0 = *(const bf16x8*)(vp + fr * 16 + G * 8);
            vf1 = *(const bf16x8*)(vp + (16 + fr) * 16 + G * 8);
        }
        f32x4 al = __builtin_amdgcn_mfma_f32_16x16x32_bf16(kf, qf, zero, 0, 0, 0);

        float mx = fmaxf(fmaxf(al[0], al[1]), fmaxf(al[2], al[3]));
        mx = fmaxf(mx, __shfl_xor(mx, 16));
        mx = fmaxf(mx, __shfl_xor(mx, 32));
        float p[4];
        #pragma unroll
        for (int r = 0; r < 4; ++r) p[r] = __expf((al[r] - mx) * 0.25f);
        float sum = p[0] + p[1] + p[2] + p[3];
        sum += __shfl_xor(sum, 16);
        sum += __shfl_xor(sum, 32);
        const float inv = 1.f / sum;

        bf16x8 paf;
        #pragma unroll
        for (int j = 0; j < 8; ++j) {
            int srcLane = fr + ((G * 8 + j) >> 2) * 16;
            float v = __shfl(p[j & 3], srcLane);
            paf[j] = (G < 2) ? (__bf16)(v * inv) : (__bf16)0.f;
        }

        acc0 = __builtin_amdgcn_mfma_f32_16x16x32_bf16(paf, vf0, acc0, 0, 0, 0);
        acc1 = __builtin_amdgcn_mfma_f32_16x16x32_bf16(paf, vf1, acc1, 0, 0, 0);
    }

    __bf16* ob = attn_bf + (size_t)d * 512;
    bf16x4 o0, o1;
    #pragma unroll
    for (int r = 0; r < 4; ++r) { o0[r] = (__bf16)acc0[r]; o1[r] = (__bf16)acc1[r]; }
    *(bf16x4*)(ob + fr * 16 + G * 4)       = o0;
    *(bf16x4*)(ob + 256 + fr * 16 + G * 4) = o1;
}

// ---------------- fused Wo-GEMM + residual + LN (+ optional chained MLP+LN) ----------------
// Phase 1: P = attn[Mx512] @ Wo[256x512]^T; x1 = LN(xres + P + xe + bo).
// CHAIN: keep x1 in LDS, x2 = LN(x1 + x1@Wm^T + mb); write x2. Else write x1.
// BM=32, 256 threads (4 waves: wave wv owns cols [wv*64, wv*64+64)). grid 313.
template<bool CHAIN>
__global__ __launch_bounds__(256) void fused_tail(
    const __bf16* __restrict__ A, const __bf16* __restrict__ W,
    const __bf16* __restrict__ xres, const __bf16* __restrict__ tb,
    const float* __restrict__ bias, const float* __restrict__ g1,
    const float* __restrict__ b1,
    const __bf16* __restrict__ Wm, const float* __restrict__ mb,
    const float* __restrict__ g2, const float* __restrict__ b2,
    float* __restrict__ outf, __bf16* __restrict__ outb, int M)
{
    __shared__ __bf16 As[32 * 64];                 // 4 KB
    __shared__ __bf16 Wsh[256 * 64];               // 32 KB (Wo tiles, reused for Wm)
    __shared__ __bf16 X1[CHAIN ? 32 * 256 : 2];    // 16 KB swizzled x1 tile
    __shared__ float sm_s[4][32];
    __shared__ float sm_q[4][32];
    const int tid = threadIdx.x;
    const int ln  = tid & 63;
    const int wv  = tid >> 6;
    const int fr  = ln & 15;
    const int kq  = ln >> 4;
    const int brow0 = blockIdx.x * 32;
    const int srow = ln >> 3;
    const int scol = ((ln & 7) ^ srow) * 8;
    char* asb = (char*)As;
    char* wsb = (char*)Wsh;
    char* x1b = (char*)X1;
    const f32x4 zero = {0.f, 0.f, 0.f, 0.f};

    f32x4 acc[2][4];
    #pragma unroll
    for (int m = 0; m < 2; ++m)
        #pragma unroll
        for (int n = 0; n < 4; ++n) acc[m][n] = zero;

    // ---- phase 1: K=512 GEMM, A+W staged per tile ----
    for (int t = 0; t < 8; ++t) {
        const int kk0 = t << 6;
        if (t) __syncthreads();
        {
            int grow = brow0 + wv * 8 + srow;
            if (grow >= M) grow = M - 1;
            gload_lds16(A + (size_t)grow * 512 + kk0 + scol, asb + wv * 1024);
        }
        #pragma unroll
        for (int c = 0; c < 8; ++c) {
            int ch = wv * 8 + c;
            gload_lds16(W + (size_t)(ch * 8 + srow) * 512 + kk0 + scol, wsb + ch * 1024);
        }
        __syncthreads();
        #pragma unroll
        for (int ks = 0; ks < 2; ++ks) {
            const int kb = ks * 64 + kq * 16;
            const int sw = (fr & 7) << 4;
            bf16x8 af0 = *(const bf16x8*)(asb + fr * 128 + (kb ^ sw));
            bf16x8 af1 = *(const bf16x8*)(asb + (16 + fr) * 128 + (kb ^ sw));
            #pragma unroll
            for (int n = 0; n < 4; ++n) {
                bf16x8 wf = *(const bf16x8*)(wsb + (wv * 64 + n * 16 + fr) * 128 + (kb ^ sw));
                acc[0][n] = __builtin_amdgcn_mfma_f32_16x16x32_bf16(af0, wf, acc[0][n], 0, 0, 0);
                acc[1][n] = __builtin_amdgcn_mfma_f32_16x16x32_bf16(af1, wf, acc[1][n], 0, 0, 0);
            }
        }
    }

    // ---- residual + LN1 ----
    float s2[2][4], q2[2][4];
    #pragma unroll
    for (int m = 0; m < 2; ++m)
        #pragma unroll
        for (int rr = 0; rr < 4; ++rr) { s2[m][rr] = 0.f; q2[m][rr] = 0.f; }
    #pragma unroll
    for (int m = 0; m < 2; ++m)
        #pragma unroll
        for (int n = 0; n < 4; ++n) {
            const int col = wv * 64 + n * 16 + fr;
            const float bi = bias[col];
            #pragma unroll
            for (int rr = 0; rr < 4; ++rr) {
                int gr = brow0 + m * 16 + kq * 4 + rr; if (gr >= M) gr = M - 1;
                float v = acc[m][n][rr] + (float)xres[(size_t)gr * 256 + col]
                          + (float)tb[(size_t)gr * 256 + col] + bi;
                acc[m][n][rr] = v;
                s2[m][rr] += v; q2[m][rr] += v * v;
            }
        }
    #pragma unroll
    for (int mask = 1; mask < 16; mask <<= 1)
        #pragma unroll
        for (int m = 0; m < 2; ++m)
            #pragma unroll
            for (int rr = 0; rr < 4; ++rr) {
                s2[m][rr] += __shfl_xor(s2[m][rr], mask);
                q2[m][rr] += __shfl_xor(q2[m][rr], mask);
            }
    if (fr == 0) {
        #pragma unroll
        for (int m = 0; m < 2; ++m)
            #pragma unroll
            for (int rr = 0; rr < 4; ++rr) {
                sm_s[wv][m * 16 + kq * 4 + rr] = s2[m][rr];
                sm_q[wv][m * 16 + kq * 4 + rr] = q2[m][rr];
            }
    }
    __syncthreads();
    float mean[2][4], invs[2][4];
    #pragma unroll
    for (int m = 0; m < 2; ++m)
        #pragma unroll
        for (int rr = 0; rr < 4; ++rr) {
            int rw = m * 16 + kq * 4 + rr;
            float ts = sm_s[0][rw] + sm_s[1][rw] + sm_s[2][rw] + sm_s[3][rw];
            float tq = sm_q[0][rw] + sm_q[1][rw] + sm_q[2][rw] + sm_q[3][rw];
            float mn = ts * (1.f / 256.f);
            mean[m][rr] = mn;
            invs[m][rr] = rsqrtf(tq * (1.f / 256.f) - mn * mn + 1e-5f);
        }

    if (!CHAIN) {
        #pragma unroll
        for (int m = 0; m < 2; ++m)
            #pragma unroll
            for (int n = 0; n < 4; ++n) {
                const int col = wv * 64 + n * 16 + fr;
                const float gv = g1[col], bv = b1[col];
                #pragma unroll
                for (int rr = 0; rr < 4; ++rr) {
                    int gr = brow0 + m * 16 + kq * 4 + rr;
                    if (gr < M) {
                        float o = (acc[m][n][rr] - mean[m][rr]) * invs[m][rr] * gv + bv;
                        outb[(size_t)gr * 256 + col] = (__bf16)o;
                        if (outf) outf[(size_t)gr * 256 + col] = o;
                    }
                }
            }
        return;
    }

    // ---- chained MLP: x1 -> LDS (swizzled), x2 = LN(x1 + x1@Wm^T + mb) ----
    #pragma unroll
    for (int m = 0; m < 2; ++m)
        #pragma unroll
        for (int n = 0; n < 4; ++n) {
            const int col = wv * 64 + n * 16 + fr;
            const float gv = g1[col], bv = b1[col];
            #pragma unroll
            for (int rr = 0; rr < 4; ++rr) {
                int row = m * 16 + kq * 4 + rr;
                float o = (acc[m][n][rr] - mean[m][rr]) * invs[m][rr] * gv + bv;
                *(__bf16*)(x1b + row * 512 + ((col * 2) ^ ((row & 7) << 4))) = (__bf16)o;
            }
        }
    __syncthreads();

    f32x4 acc2[2][4];
    #pragma unroll
    for (int m = 0; m < 2; ++m)
        #pragma unroll
        for (int n = 0; n < 4; ++n) acc2[m][n] = zero;

    for (int t = 0; t < 4; ++t) {
        if (t) __syncthreads();
        #pragma unroll
        for (int c = 0; c < 8; ++c) {
            int ch = wv * 8 + c;
            gload_lds16(Wm + (size_t)(ch * 8 + srow) * 256 + t * 64 + scol, wsb + ch * 1024);
        }
        __syncthreads();
        #pragma unroll
        for (int ks = 0; ks < 2; ++ks) {
            const int kb = t * 128 + ks * 64 + kq * 16;
            const int sw = (fr & 7) << 4;
            bf16x8 af0 = *(const bf16x8*)(x1b + fr * 512 + (kb ^ sw));
            bf16x8 af1 = *(const bf16x8*)(x1b + (16 + fr) * 512 + (kb ^ ((fr & 7) << 4)));
            const int kbl = ks * 64 + kq * 16;
            #pragma unroll
            for (int n = 0; n < 4; ++n) {
                bf16x8 wf = *(const bf16x8*)(wsb + (wv * 64 + n * 16 + fr) * 128 + (kbl ^ sw));
                acc2[0][n] = __builtin_amdgcn_mfma_f32_16x16x32_bf16(af0, wf, acc2[0][n], 0, 0, 0);
                acc2[1][n] = __builtin_amdgcn_mfma_f32_16x16x32_bf16(af1, wf, acc2[1][n], 0, 0, 0);
            }
        }
    }

    #pragma unroll
    for (int m = 0; m < 2; ++m)
        #pragma unroll
        for (int rr = 0; rr < 4; ++rr) { s2[m][rr] = 0.f; q2[m][rr] = 0.f; }
    #pragma unroll
    for (int m = 0; m < 2; ++m)
        #pragma unroll
        for (int n = 0; n < 4; ++n) {
            const int col = wv * 64 + n * 16 + fr;
            const float bi = mb[col];
            #pragma unroll
            for (int rr = 0; rr < 4; ++rr) {
                int row = m * 16 + kq * 4 + rr;
                float x1v = (float)*(const __bf16*)(x1b + row * 512 + ((col * 2) ^ ((row & 7) << 4)));
                float v = acc2[m][n][rr] + x1v + bi;
                acc2[m][n][rr] = v;
                s2[m][rr] += v; q2[m][rr] += v * v;
            }
        }
    #pragma unroll
    for (int mask = 1; mask < 16; mask <<= 1)
        #pragma unroll
        for (int m = 0; m < 2; ++m)
            #pragma unroll
            for (int rr = 0; rr < 4; ++rr) {
                s2[m][rr] += __shfl_xor(s2[m][rr], mask);
                q2[m][rr] += __shfl_xor(q2[m][rr], mask);
            }
    __syncthreads();   // sm_s reuse: ensure all LN1 reads are done
    if (fr == 0) {
        #pragma unroll
        for (int m = 0; m < 2; ++m)
            #pragma unroll
            for (int rr = 0; rr < 4; ++rr) {
                sm_s[wv][m * 16 + kq * 4 + rr] = s2[m][rr];
                sm_q[wv][m * 16 + kq * 4 + rr] = q2[m][rr];
            }
    }
    __syncthreads();
    #pragma unroll
    for (int m = 0; m < 2; ++m)
        #pragma unroll
        for (int rr = 0; rr < 4; ++rr) {
            int rw = m * 16 + kq * 4 + rr;
            float ts = sm_s[0][rw] + sm_s[1][rw] + sm_s[2][rw] + sm_s[3][rw];
            float tq = sm_q[0][rw] + sm_q[1][rw] + sm_q[2][rw] + sm_q[3][rw];
            float mn = ts * (1.f / 256.f);
            mean[m][rr] = mn;
            invs[m][rr] = rsqrtf(tq * (1.f / 256.f) - mn * mn + 1e-5f);
        }
    #pragma unroll
    for (int m = 0; m < 2; ++m)
        #pragma unroll
        for (int n = 0; n < 4; ++n) {
            const int col = wv * 64 + n * 16 + fr;
            const float gv = g2[col], bv = b2[col];
            #pragma unroll
            for (int rr = 0; rr < 4; ++rr) {
                int gr = brow0 + m * 16 + kq * 4 + rr;
                if (gr < M) {
                    float o = (acc2[m][n][rr] - mean[m][rr]) * invs[m][rr] * gv + bv;
                    outb[(size_t)gr * 256 + col] = (__bf16)o;
                    if (outf) outf[(size_t)gr * 256 + col] = o;
                }
            }
        }
}

extern "C" void kernel_launch(void* const* d_in, const int* in_sizes, int n_in,
                              void* d_out, int out_size, void* d_ws, size_t ws_size,
                              hipStream_t stream)
{
    const int*   eidx = (const int*)  d_in[0];
    const float* x_in = (const float*)d_in[1];
    const float* We   = (const float*)d_in[2];
    const float* Wq   = (const float*)d_in[3];
    const float* Wk   = (const float*)d_in[4];
    const float* Wv   = (const float*)d_in[5];
    const float* Wo   = (const float*)d_in[6];
    const float* bo   = (const float*)d_in[7];
    const float* lng  = (const float*)d_in[8];
    const float* lnb  = (const float*)d_in[9];
    const float* mlpW = (const float*)d_in[10];
    const float* mlpb = (const float*)d_in[11];
    float* out = (float*)d_out;

    char* p = (char*)d_ws;
    __bf16* wMerged = (__bf16*)p; p += (size_t)10 * 458752 * 2;  // [10][1792][256]
    __bf16* wQKVtmp = (__bf16*)p; p += (size_t)10 * 393216 * 2;
    __bf16* wET     = (__bf16*)p; p += (size_t)10 * 65536  * 2;
    __bf16* wO      = (__bf16*)p; p += (size_t)10 * 131072 * 2;
    __bf16* wM      = (__bf16*)p; p += (size_t)5  * 65536  * 2;
    __bf16* qkv     = (__bf16*)p; p += (size_t)N_NODES * 1536 * 2;
    __bf16* attn_bf = (__bf16*)p; p += (size_t)N_NODES * 512 * 2;
    __bf16* xeb     = (__bf16*)p; p += (size_t)N_NODES * 256 * 2;
    __bf16* xbb     = (__bf16*)p; p += (size_t)N_NODES * 256 * 2;
    int* counts  = (int*)p;    p += (size_t)(N_NODES + 16) * 4;
    int* csr_off = (int*)p;    p += (size_t)(N_NODES + 16) * 4;
    int* csr_wrk = (int*)p;    p += (size_t)(N_NODES + 16) * 4;
    int* csr_src = (int*)p;    p += (size_t)N_EDGES * 4;
    if ((size_t)(p - (char*)d_ws) > ws_size) return;

    dim3 blk(256);

    // ---- prep: CSR + weight conversion ----
    hipMemsetAsync(counts, 0, (size_t)(N_NODES + 16) * 4, stream);
    hist_dst<<<dim3(157), blk, 0, stream>>>(eidx, counts);
    scan_offsets<<<dim3(1), blk, 0, stream>>>(counts, csr_off, csr_wrk, N_NODES);
    scatter_csr<<<dim3(157), blk, 0, stream>>>(eidx, csr_wrk, csr_src);

    prep_cvt<<<dim3(128, 7), blk, 0, stream>>>(We, Wq, Wk, Wv, Wo, mlpW, x_in,
                                               wMerged, wQKVtmp, wO, wM, xbb);
    transpose_we<<<dim3(16, 10), blk, 0, stream>>>(We, wET);

    // W'[l] = Wqkv_perm[l] @ We[l] -> wMerged rows 256..1791 (batched)
    gemm_lds<1, 64><<<dim3(4, 12, 10), blk, 0, stream>>>(
        wQKVtmp, wET, nullptr, wMerged + 65536, 1536, 256, 256,
        393216, 65536, 458752);

    dim3 gMerged(14, 79);   // BN=128, Nc=1792

    for (int l = 0; l < NLAYERS; ++l) {
        for (int s = 0; s < 2; ++s) {
            size_t ls = (size_t)(l * 2 + s);
            // xe | Q^T|K^T|V = x @ [We; Wqkv@We]^T  (one GEMM)
            gemm_lds<3, 128><<<gMerged, blk, 0, stream>>>(
                xbb, wMerged + ls * 458752, (float*)qkv, xeb, N_NODES, 256, 0, 0, 0, 0);
            edge_attn_csr<<<dim3(N_NODES / 4), blk, 0, stream>>>(csr_off, csr_src,
                                                                 qkv, attn_bf);
            if (s == 0) {
                fused_tail<false><<<dim3(313), blk, 0, stream>>>(
                    attn_bf, wO + ls * 131072, xbb, xeb, bo + ls * 256,
                    lng + (size_t)(l * 3) * 256, lnb + (size_t)(l * 3) * 256,
                    nullptr, nullptr, nullptr, nullptr,
                    nullptr, xbb, N_NODES);
            } else {
                bool lastL = (l == NLAYERS - 1);
                fused_tail<true><<<dim3(313), blk, 0, stream>>>(
                    attn_bf, wO + ls * 131072, xbb, xeb, bo + ls * 256,
                    lng + (size_t)(l * 3 + 1) * 256, lnb + (size_t)(l * 3 + 1) * 256,
                    wM + (size_t)l * 65536, mlpb + (size_t)l * 256,
                    lng + (size_t)(l * 3 + 2) * 256, lnb + (size_t)(l * 3 + 2) * 256,
                    lastL ? out : nullptr, xbb, N_NODES);
            }
        }
    }
}

// Round 14
// 649.162 us; speedup vs baseline: 1.3048x; 1.0144x over previous
//
#include <hip/hip_runtime.h>
#include <hip/hip_bf16.h>

#define N_NODES 10000
#define N_EDGES 40000
#define NLAYERS 5

typedef __bf16 bf16x8 __attribute__((ext_vector_type(8)));
typedef __bf16 bf16x4 __attribute__((ext_vector_type(4)));
typedef float  f32x4  __attribute__((ext_vector_type(4)));

__device__ __forceinline__ bf16x8 cvt8(float4 a, float4 b) {
    bf16x8 r;
    r[0] = (__bf16)a.x; r[1] = (__bf16)a.y; r[2] = (__bf16)a.z; r[3] = (__bf16)a.w;
    r[4] = (__bf16)b.x; r[5] = (__bf16)b.y; r[6] = (__bf16)b.z; r[7] = (__bf16)b.w;
    return r;
}

__device__ __forceinline__ void gload_lds16(const void* g, void* l) {
    __builtin_amdgcn_global_load_lds(
        (const __attribute__((address_space(1))) void*)g,
        (__attribute__((address_space(3))) void*)l, 16, 0, 0);
}

// T1: bijective XCD-aware block swizzle (m204). Pure relabeling — correctness-safe.
__device__ __forceinline__ int xcd_swz(int flat, int nwg) {
    int xcd = flat & 7;
    int idx = flat >> 3;
    int q = nwg >> 3, r = nwg & 7;
    return (xcd < r ? xcd * (q + 1) : r * (q + 1) + (xcd - r) * q) + idx;
}

// ---------------- all f32->bf16 weight/x conversions in ONE kernel ----------------
__global__ __launch_bounds__(256) void prep_cvt(
    const float* __restrict__ We, const float* __restrict__ Wq,
    const float* __restrict__ Wk, const float* __restrict__ Wv,
    const float* __restrict__ Wo, const float* __restrict__ mlpW,
    const float* __restrict__ x_in,
    __bf16* __restrict__ wMerged, __bf16* __restrict__ wQKVtmp,
    __bf16* __restrict__ wOd, __bf16* __restrict__ wMd, __bf16* __restrict__ xbb)
{
    const int reg = blockIdx.y;
    long i0 = (long)blockIdx.x * blockDim.x + threadIdx.x;
    long stride = (long)gridDim.x * blockDim.x;
    if (reg == 0) {                       // We -> wMerged rows 0..255 (stride 458752)
        for (long i = i0; i < 81920; i += stride) {
            long e = i * 8; long ch = e >> 16; long r = e & 65535;
            *(bf16x8*)(wMerged + ch * 458752 + r) =
                cvt8(*(const float4*)(We + e), *(const float4*)(We + e + 4));
        }
    } else if (reg == 1 || reg == 2) {    // Wq/Wk row-permuted
        const float* S = (reg == 1) ? Wq : Wk;
        __bf16* D = wQKVtmp + ((reg == 2) ? 131072 : 0);
        for (long i = i0; i < 163840; i += stride) {
            long e = i * 8;
            int slot = (int)(e >> 17); int rem = (int)(e & 131071);
            int row = rem >> 8; int col = rem & 255;
            int srow = ((row & 31) << 4) | (row >> 5);
            const float* sp = S + ((long)slot << 17) + ((long)srow << 8) + col;
            *(bf16x8*)(D + (long)slot * 393216 + ((long)row << 8) + col) =
                cvt8(*(const float4*)sp, *(const float4*)(sp + 4));
        }
    } else if (reg == 3) {                // Wv
        for (long i = i0; i < 163840; i += stride) {
            long e = i * 8; long ch = e >> 17; long r = e & 131071;
            *(bf16x8*)(wQKVtmp + 262144 + ch * 393216 + r) =
                cvt8(*(const float4*)(Wv + e), *(const float4*)(Wv + e + 4));
        }
    } else if (reg == 4) {                // Wo flat
        for (long i = i0; i < 163840; i += stride) {
            long e = i * 8;
            *(bf16x8*)(wOd + e) =
                cvt8(*(const float4*)(Wo + e), *(const float4*)(Wo + e + 4));
        }
    } else if (reg == 5) {                // mlpW flat
        for (long i = i0; i < 40960; i += stride) {
            long e = i * 8;
            *(bf16x8*)(wMd + e) =
                cvt8(*(const float4*)(mlpW + e), *(const float4*)(mlpW + e + 4));
        }
    } else {                              // x_in flat
        for (long i = i0; i < 320000; i += stride) {
            long e = i * 8;
            *(bf16x8*)(xbb + e) =
                cvt8(*(const float4*)(x_in + e), *(const float4*)(x_in + e + 4));
        }
    }
}

// WeT[slot][n][k] = We[slot][k][n], bf16. grid (16, 10).
__global__ __launch_bounds__(256) void transpose_we(
    const float* __restrict__ S, __bf16* __restrict__ D)
{
    __shared__ float tile[64][65];
    const int slot = blockIdx.y;
    const int tx = blockIdx.x & 3, ty = blockIdx.x >> 2;
    const float* sp = S + (size_t)slot * 65536 + (size_t)(ty * 64) * 256 + tx * 64;
    const int t = threadIdx.x;
    #pragma unroll
    for (int j = 0; j < 16; ++j) {
        int idx = t + 256 * j;
        int r = idx >> 6, c = idx & 63;
        tile[r][c] = sp[r * 256 + c];
    }
    __syncthreads();
    __bf16* dp = D + (size_t)slot * 65536 + (size_t)(tx * 64) * 256 + ty * 64;
    #pragma unroll
    for (int j = 0; j < 16; ++j) {
        int idx = t + 256 * j;
        int nl = idx >> 6, kl = idx & 63;
        dp[nl * 256 + kl] = (__bf16)tile[kl][nl];
    }
}

// ---------------- CSR build ----------------
__global__ __launch_bounds__(256) void hist_dst(
    const int* __restrict__ eidx, int* __restrict__ counts)
{
    int e = blockIdx.x * 256 + threadIdx.x;
    if (e < N_EDGES) atomicAdd(&counts[eidx[N_EDGES + e]], 1);
}

__global__ __launch_bounds__(256) void scan_offsets(
    const int* __restrict__ counts, int* __restrict__ offs,
    int* __restrict__ wrk, int n)
{
    const int tid = threadIdx.x;
    const int base = tid * 40;
    int local[40];
    int s = 0;
    #pragma unroll
    for (int j = 0; j < 40; ++j) {
        int i = base + j;
        int v = (i < n) ? counts[i] : 0;
        local[j] = s; s += v;
    }
    __shared__ int sm[256];
    sm[tid] = s;
    __syncthreads();
    for (int off = 1; off < 256; off <<= 1) {
        int t2 = (tid >= off) ? sm[tid - off] : 0;
        __syncthreads();
        sm[tid] += t2;
        __syncthreads();
    }
    int pre = (tid == 0) ? 0 : sm[tid - 1];
    #pragma unroll
    for (int j = 0; j < 40; ++j) {
        int i = base + j;
        if (i < n) { int v = pre + local[j]; offs[i] = v; wrk[i] = v; }
    }
    if (tid == 255) offs[n] = sm[255];
}

__global__ __launch_bounds__(256) void scatter_csr(
    const int* __restrict__ eidx, int* __restrict__ wrk, int* __restrict__ csr_src)
{
    int e = blockIdx.x * 256 + threadIdx.x;
    if (e < N_EDGES) {
        int sn = eidx[e];
        int d  = eidx[N_EDGES + e];
        int pos = atomicAdd(&wrk[d], 1);
        csr_src[pos] = sn;
    }
}

// ---------------- LDS-staged bf16 GEMM (merged x->xe|QKV + weight prep) ----------------
template<int MODE, int BN>
__global__ __launch_bounds__(256) void gemm_lds(
    const __bf16* __restrict__ A, const __bf16* __restrict__ W,
    float* __restrict__ Cf, __bf16* __restrict__ Ch,
    int M, int K, int ldc, long sA, long sW, long sC)
{
    __shared__ __bf16 As[128 * 64];
    __shared__ __bf16 Wsh[BN * 64];
    constexpr int NF = BN / 32;
    A += (long)blockIdx.z * sA;
    W += (long)blockIdx.z * sW;
    if (Ch) Ch += (long)blockIdx.z * sC;
    const int tid = threadIdx.x;
    const int ln  = tid & 63;
    const int wv  = tid >> 6;
    const int wr  = wv >> 1, wc = wv & 1;

    // T1 XCD swizzle of the (x,y) block coordinates (bijective, perf-only)
    const int nx = gridDim.x, nwg = nx * gridDim.y;
    const int swz = xcd_swz(blockIdx.y * nx + blockIdx.x, nwg);
    const int brow0 = (swz / nx) * 128;
    const int colb0 = (swz % nx) * BN;

    const int srow = ln >> 3;
    const int scol = ((ln & 7) ^ srow) * 8;
    const int fr = ln & 15;
    const int kq = ln >> 4;
    char* asb = (char*)As;
    char* wsb = (char*)Wsh;

    f32x4 acc[4][NF];
    #pragma unroll
    for (int m = 0; m < 4; ++m)
        #pragma unroll
        for (int n = 0; n < NF; ++n) acc[m][n] = (f32x4){0.f, 0.f, 0.f, 0.f};

    const int nt = K >> 6;
    for (int t = 0; t < nt; ++t) {
        const int kk0 = t << 6;
        if (t) __syncthreads();
        #pragma unroll
        for (int c = 0; c < 4; ++c) {
            int ch = wv * 4 + c;
            int grow = brow0 + ch * 8 + srow;
            if (grow >= M) grow = M - 1;
            gload_lds16(A + (size_t)grow * K + kk0 + scol, asb + ch * 1024);
        }
        #pragma unroll
        for (int c = 0; c < NF; ++c) {
            int ch = wv * NF + c;
            int grow = colb0 + ch * 8 + srow;
            gload_lds16(W + (size_t)grow * K + kk0 + scol, wsb + ch * 1024);
        }
        __syncthreads();
        #pragma unroll
        for (int ks = 0; ks < 2; ++ks) {
            const int kb = ks * 64 + kq * 16;
            const int sw = (fr & 7) << 4;
            bf16x8 af[4], wf[NF];
            #pragma unroll
            for (int m = 0; m < 4; ++m) {
                int row = wr * 64 + m * 16 + fr;
                af[m] = *(const bf16x8*)(asb + row * 128 + (kb ^ sw));
            }
            #pragma unroll
            for (int n = 0; n < NF; ++n) {
                int row = wc * (BN / 2) + n * 16 + fr;
                wf[n] = *(const bf16x8*)(wsb + row * 128 + (kb ^ sw));
            }
            #pragma unroll
            for (int m = 0; m < 4; ++m)
                #pragma unroll
                for (int n = 0; n < NF; ++n)
                    acc[m][n] = __builtin_amdgcn_mfma_f32_16x16x32_bf16(
                        af[m], wf[n], acc[m][n], 0, 0, 0);
        }
    }

    const int rq = (ln >> 4) * 4;
    #pragma unroll
    for (int m = 0; m < 4; ++m) {
        #pragma unroll
        for (int rr = 0; rr < 4; ++rr) {
            int orow = brow0 + wr * 64 + m * 16 + rq + rr;
            if (orow < M) {
                #pragma unroll
                for (int n = 0; n < NF; ++n) {
                    int c = colb0 + wc * (BN / 2) + fr + n * 16;
                    if (MODE == 0)      Cf[(size_t)orow * ldc + c] = acc[m][n][rr];
                    else if (MODE == 1) Ch[(size_t)orow * ldc + c] = (__bf16)acc[m][n][rr];
                    else {
                        if (c < 256) Ch[(size_t)orow * 256 + c] = (__bf16)acc[m][n][rr];
                        else ((__bf16*)Cf)[(size_t)orow * 1536 + (c - 256)] = (__bf16)acc[m][n][rr];
                    }
                }
            }
        }
    }
}

// ---------------- per-dst attention via MFMA, one wave per node ----------------
// qkv per node (1536 bf16): Q^T[16a][32h] | K^T[16a][32h] | V[32h][16b].
__global__ __launch_bounds__(256) void edge_attn_csr(
    const int* __restrict__ csr_off, const int* __restrict__ csr_src,
    const __bf16* __restrict__ qkv, __bf16* __restrict__ attn_bf)
{
    const int lane = threadIdx.x & 63;
    const int blk = xcd_swz(blockIdx.x, gridDim.x);   // T1: contiguous nodes/XCD
    const int d = blk * 4 + (threadIdx.x >> 6);
    const int fr = lane & 15;
    const int G  = lane >> 4;

    const __bf16* qT = qkv + (size_t)d * 1536;
    const bf16x8 qf = *(const bf16x8*)(qT + fr * 32 + G * 8);

    const f32x4 zero = {0.f, 0.f, 0.f, 0.f};
    f32x4 acc0 = zero, acc1 = zero;

    const int i0 = csr_off[d], i1 = csr_off[d + 1];
    int sN = (i0 < i1) ? csr_src[i0] : 0;
    bf16x8 kfN = *(const bf16x8*)(qkv + (size_t)sN * 1536 + 512 + fr * 32 + G * 8);
    for (int i = i0; i < i1; ++i) {
        const int s = sN;
        const bf16x8 kf = kfN;
        if (i + 1 < i1) {
            sN = csr_src[i + 1];
            kfN = *(const bf16x8*)(qkv + (size_t)sN * 1536 + 512 + fr * 32 + G * 8);
        }
        const __bf16* vp = qkv + (size_t)s * 1536 + 1024;
        bf16x8 vf0 = {0, 0, 0, 0, 0, 0, 0, 0};
        bf16x8 vf1 = {0, 0, 0, 0, 0, 0, 0, 0};
        if (G < 2) {
            vf0 = *(const bf16x8*)(vp + fr * 16 + G * 8);
            vf1 = *(const bf16x8*)(vp + (16 + fr) * 16 + G * 8);
        }
        f32x4 al = __builtin_amdgcn_mfma_f32_16x16x32_bf16(kf, qf, zero, 0, 0, 0);

        float mx = fmaxf(fmaxf(al[0], al[1]), fmaxf(al[2], al[3]));
        mx = fmaxf(mx, __shfl_xor(mx, 16));
        mx = fmaxf(mx, __shfl_xor(mx, 32));
        float p[4];
        #pragma unroll
        for (int r = 0; r < 4; ++r) p[r] = __expf((al[r] - mx) * 0.25f);
        float sum = p[0] + p[1] + p[2] + p[3];
        sum += __shfl_xor(sum, 16);
        sum += __shfl_xor(sum, 32);
        const float inv = 1.f / sum;

        bf16x8 paf;
        #pragma unroll
        for (int j = 0; j < 8; ++j) {
            int srcLane = fr + ((G * 8 + j) >> 2) * 16;
            float v = __shfl(p[j & 3], srcLane);
            paf[j] = (G < 2) ? (__bf16)(v * inv) : (__bf16)0.f;
        }

        acc0 = __builtin_amdgcn_mfma_f32_16x16x32_bf16(paf, vf0, acc0, 0, 0, 0);
        acc1 = __builtin_amdgcn_mfma_f32_16x16x32_bf16(paf, vf1, acc1, 0, 0, 0);
    }

    __bf16* ob = attn_bf + (size_t)d * 512;
    bf16x4 o0, o1;
    #pragma unroll
    for (int r = 0; r < 4; ++r) { o0[r] = (__bf16)acc0[r]; o1[r] = (__bf16)acc1[r]; }
    *(bf16x4*)(ob + fr * 16 + G * 4)       = o0;
    *(bf16x4*)(ob + 256 + fr * 16 + G * 4) = o1;
}

// ---------------- fused Wo-GEMM + residual + LN (+ optional chained MLP+LN) ----------------
// Phase 1: P = attn[Mx512] @ Wo[256x512]^T; x1 = LN(xres + P + xe + bo).
// CHAIN: keep x1 in LDS, x2 = LN(x1 + x1@Wm^T + mb); write x2. Else write x1.
// BM=16 (grid 625, 2.4 waves/SIMD), 256 threads: wave wv owns cols
// [wv*64, wv*64+64). Same per-row arithmetic/order as the BM=32 version.
template<bool CHAIN>
__global__ __launch_bounds__(256) void fused_tail(
    const __bf16* __restrict__ A, const __bf16* __restrict__ W,
    const __bf16* __restrict__ xres, const __bf16* __restrict__ tb,
    const float* __restrict__ bias, const float* __restrict__ g1,
    const float* __restrict__ b1,
    const __bf16* __restrict__ Wm, const float* __restrict__ mb,
    const float* __restrict__ g2, const float* __restrict__ b2,
    float* __restrict__ outf, __bf16* __restrict__ outb, int M)
{
    __shared__ __bf16 As[16 * 64];                 // 2 KB
    __shared__ __bf16 Wsh[256 * 64];               // 32 KB (Wo tiles, reused for Wm)
    __shared__ __bf16 X1[CHAIN ? 16 * 256 : 2];    // 8 KB swizzled x1 tile
    __shared__ float sm_s[4][16];
    __shared__ float sm_q[4][16];
    const int tid = threadIdx.x;
    const int ln  = tid & 63;
    const int wv  = tid >> 6;
    const int fr  = ln & 15;
    const int kq  = ln >> 4;
    const int brow0 = blockIdx.x * 16;
    const int srow = ln >> 3;
    const int scol = ((ln & 7) ^ srow) * 8;
    char* asb = (char*)As;
    char* wsb = (char*)Wsh;
    char* x1b = (char*)X1;
    const f32x4 zero = {0.f, 0.f, 0.f, 0.f};

    f32x4 acc[4];
    #pragma unroll
    for (int n = 0; n < 4; ++n) acc[n] = zero;

    // ---- phase 1: K=512 GEMM, A+W staged per tile ----
    for (int t = 0; t < 8; ++t) {
        const int kk0 = t << 6;
        if (t) __syncthreads();
        if (wv < 2) {
            int grow = brow0 + wv * 8 + srow;
            if (grow >= M) grow = M - 1;
            gload_lds16(A + (size_t)grow * 512 + kk0 + scol, asb + wv * 1024);
        }
        #pragma unroll
        for (int c = 0; c < 8; ++c) {
            int ch = wv * 8 + c;
            gload_lds16(W + (size_t)(ch * 8 + srow) * 512 + kk0 + scol, wsb + ch * 1024);
        }
        __syncthreads();
        #pragma unroll
        for (int ks = 0; ks < 2; ++ks) {
            const int kb = ks * 64 + kq * 16;
            const int sw = (fr & 7) << 4;
            bf16x8 af = *(const bf16x8*)(asb + fr * 128 + (kb ^ sw));
            #pragma unroll
            for (int n = 0; n < 4; ++n) {
                bf16x8 wf = *(const bf16x8*)(wsb + (wv * 64 + n * 16 + fr) * 128 + (kb ^ sw));
                acc[n] = __builtin_amdgcn_mfma_f32_16x16x32_bf16(af, wf, acc[n], 0, 0, 0);
            }
        }
    }

    // ---- residual + LN1 ----
    float s2[4] = {0.f, 0.f, 0.f, 0.f}, q2[4] = {0.f, 0.f, 0.f, 0.f};
    #pragma unroll
    for (int n = 0; n < 4; ++n) {
        const int col = wv * 64 + n * 16 + fr;
        const float bi = bias[col];
        #pragma unroll
        for (int rr = 0; rr < 4; ++rr) {
            int gr = brow0 + kq * 4 + rr; if (gr >= M) gr = M - 1;
            float v = acc[n][rr] + (float)xres[(size_t)gr * 256 + col]
                      + (float)tb[(size_t)gr * 256 + col] + bi;
            acc[n][rr] = v;
            s2[rr] += v; q2[rr] += v * v;
        }
    }
    #pragma unroll
    for (int mask = 1; mask < 16; mask <<= 1)
        #pragma unroll
        for (int rr = 0; rr < 4; ++rr) {
            s2[rr] += __shfl_xor(s2[rr], mask);
            q2[rr] += __shfl_xor(q2[rr], mask);
        }
    if (fr == 0) {
        #pragma unroll
        for (int rr = 0; rr < 4; ++rr) {
            sm_s[wv][kq * 4 + rr] = s2[rr];
            sm_q[wv][kq * 4 + rr] = q2[rr];
        }
    }
    __syncthreads();
    float mean[4], invs[4];
    #pragma unroll
    for (int rr = 0; rr < 4; ++rr) {
        int rw = kq * 4 + rr;
        float ts = sm_s[0][rw] + sm_s[1][rw] + sm_s[2][rw] + sm_s[3][rw];
        float tq = sm_q[0][rw] + sm_q[1][rw] + sm_q[2][rw] + sm_q[3][rw];
        float mn = ts * (1.f / 256.f);
        mean[rr] = mn;
        invs[rr] = rsqrtf(tq * (1.f / 256.f) - mn * mn + 1e-5f);
    }

    if (!CHAIN) {
        #pragma unroll
        for (int n = 0; n < 4; ++n) {
            const int col = wv * 64 + n * 16 + fr;
            const float gv = g1[col], bv = b1[col];
            #pragma unroll
            for (int rr = 0; rr < 4; ++rr) {
                int gr = brow0 + kq * 4 + rr;
                if (gr < M) {
                    float o = (acc[n][rr] - mean[rr]) * invs[rr] * gv + bv;
                    outb[(size_t)gr * 256 + col] = (__bf16)o;
                    if (outf) outf[(size_t)gr * 256 + col] = o;
                }
            }
        }
        return;
    }

    // ---- chained MLP: x1 -> LDS (swizzled), x2 = LN(x1 + x1@Wm^T + mb) ----
    #pragma unroll
    for (int n = 0; n < 4; ++n) {
        const int col = wv * 64 + n * 16 + fr;
        const float gv = g1[col], bv = b1[col];
        #pragma unroll
        for (int rr = 0; rr < 4; ++rr) {
            int row = kq * 4 + rr;
            float o = (acc[n][rr] - mean[rr]) * invs[rr] * gv + bv;
            *(__bf16*)(x1b + row * 512 + ((col * 2) ^ ((row & 7) << 4))) = (__bf16)o;
        }
    }
    __syncthreads();

    f32x4 acc2[4];
    #pragma unroll
    for (int n = 0; n < 4; ++n) acc2[n] = zero;

    for (int t = 0; t < 4; ++t) {
        if (t) __syncthreads();
        #pragma unroll
        for (int c = 0; c < 8; ++c) {
            int ch = wv * 8 + c;
            gload_lds16(Wm + (size_t)(ch * 8 + srow) * 256 + t * 64 + scol, wsb + ch * 1024);
        }
        __syncthreads();
        #pragma unroll
        for (int ks = 0; ks < 2; ++ks) {
            const int kb = t * 128 + ks * 64 + kq * 16;
            const int sw = (fr & 7) << 4;
            bf16x8 af = *(const bf16x8*)(x1b + fr * 512 + (kb ^ sw));
            const int kbl = ks * 64 + kq * 16;
            #pragma unroll
            for (int n = 0; n < 4; ++n) {
                bf16x8 wf = *(const bf16x8*)(wsb + (wv * 64 + n * 16 + fr) * 128 + (kbl ^ sw));
                acc2[n] = __builtin_amdgcn_mfma_f32_16x16x32_bf16(af, wf, acc2[n], 0, 0, 0);
            }
        }
    }

    float s3[4] = {0.f, 0.f, 0.f, 0.f}, q3[4] = {0.f, 0.f, 0.f, 0.f};
    #pragma unroll
    for (int n = 0; n < 4; ++n) {
        const int col = wv * 64 + n * 16 + fr;
        const float bi = mb[col];
        #pragma unroll
        for (int rr = 0; rr < 4; ++rr) {
            int row = kq * 4 + rr;
            float x1v = (float)*(const __bf16*)(x1b + row * 512 + ((col * 2) ^ ((row & 7) << 4)));
            float v = acc2[n][rr] + x1v + bi;
            acc2[n][rr] = v;
            s3[rr] += v; q3[rr] += v * v;
        }
    }
    #pragma unroll
    for (int mask = 1; mask < 16; mask <<= 1)
        #pragma unroll
        for (int rr = 0; rr < 4; ++rr) {
            s3[rr] += __shfl_xor(s3[rr], mask);
            q3[rr] += __shfl_xor(q3[rr], mask);
        }
    __syncthreads();   // sm_s reuse: ensure all LN1 reads are done
    if (fr == 0) {
        #pragma unroll
        for (int rr = 0; rr < 4; ++rr) {
            sm_s[wv][kq * 4 + rr] = s3[rr];
            sm_q[wv][kq * 4 + rr] = q3[rr];
        }
    }
    __syncthreads();
    #pragma unroll
    for (int rr = 0; rr < 4; ++rr) {
        int rw = kq * 4 + rr;
        float ts = sm_s[0][rw] + sm_s[1][rw] + sm_s[2][rw] + sm_s[3][rw];
        float tq = sm_q[0][rw] + sm_q[1][rw] + sm_q[2][rw] + sm_q[3][rw];
        float mn = ts * (1.f / 256.f);
        mean[rr] = mn;
        invs[rr] = rsqrtf(tq * (1.f / 256.f) - mn * mn + 1e-5f);
    }
    #pragma unroll
    for (int n = 0; n < 4; ++n) {
        const int col = wv * 64 + n * 16 + fr;
        const float gv = g2[col], bv = b2[col];
        #pragma unroll
        for (int rr = 0; rr < 4; ++rr) {
            int gr = brow0 + kq * 4 + rr;
            if (gr < M) {
                float o = (acc2[n][rr] - mean[rr]) * invs[rr] * gv + bv;
                outb[(size_t)gr * 256 + col] = (__bf16)o;
                if (outf) outf[(size_t)gr * 256 + col] = o;
            }
        }
    }
}

extern "C" void kernel_launch(void* const* d_in, const int* in_sizes, int n_in,
                              void* d_out, int out_size, void* d_ws, size_t ws_size,
                              hipStream_t stream)
{
    const int*   eidx = (const int*)  d_in[0];
    const float* x_in = (const float*)d_in[1];
    const float* We   = (const float*)d_in[2];
    const float* Wq   = (const float*)d_in[3];
    const float* Wk   = (const float*)d_in[4];
    const float* Wv   = (const float*)d_in[5];
    const float* Wo   = (const float*)d_in[6];
    const float* bo   = (const float*)d_in[7];
    const float* lng  = (const float*)d_in[8];
    const float* lnb  = (const float*)d_in[9];
    const float* mlpW = (const float*)d_in[10];
    const float* mlpb = (const float*)d_in[11];
    float* out = (float*)d_out;

    char* p = (char*)d_ws;
    __bf16* wMerged = (__bf16*)p; p += (size_t)10 * 458752 * 2;  // [10][1792][256]
    __bf16* wQKVtmp = (__bf16*)p; p += (size_t)10 * 393216 * 2;
    __bf16* wET     = (__bf16*)p; p += (size_t)10 * 65536  * 2;
    __bf16* wO      = (__bf16*)p; p += (size_t)10 * 131072 * 2;
    __bf16* wM      = (__bf16*)p; p += (size_t)5  * 65536  * 2;
    __bf16* qkv     = (__bf16*)p; p += (size_t)N_NODES * 1536 * 2;
    __bf16* attn_bf = (__bf16*)p; p += (size_t)N_NODES * 512 * 2;
    __bf16* xeb     = (__bf16*)p; p += (size_t)N_NODES * 256 * 2;
    __bf16* xbb     = (__bf16*)p; p += (size_t)N_NODES * 256 * 2;
    int* counts  = (int*)p;    p += (size_t)(N_NODES + 16) * 4;
    int* csr_off = (int*)p;    p += (size_t)(N_NODES + 16) * 4;
    int* csr_wrk = (int*)p;    p += (size_t)(N_NODES + 16) * 4;
    int* csr_src = (int*)p;    p += (size_t)N_EDGES * 4;
    if ((size_t)(p - (char*)d_ws) > ws_size) return;

    dim3 blk(256);

    // ---- prep: CSR + weight conversion ----
    hipMemsetAsync(counts, 0, (size_t)(N_NODES + 16) * 4, stream);
    hist_dst<<<dim3(157), blk, 0, stream>>>(eidx, counts);
    scan_offsets<<<dim3(1), blk, 0, stream>>>(counts, csr_off, csr_wrk, N_NODES);
    scatter_csr<<<dim3(157), blk, 0, stream>>>(eidx, csr_wrk, csr_src);

    prep_cvt<<<dim3(128, 7), blk, 0, stream>>>(We, Wq, Wk, Wv, Wo, mlpW, x_in,
                                               wMerged, wQKVtmp, wO, wM, xbb);
    transpose_we<<<dim3(16, 10), blk, 0, stream>>>(We, wET);

    // W'[l] = Wqkv_perm[l] @ We[l] -> wMerged rows 256..1791 (batched)
    gemm_lds<1, 64><<<dim3(4, 12, 10), blk, 0, stream>>>(
        wQKVtmp, wET, nullptr, wMerged + 65536, 1536, 256, 256,
        393216, 65536, 458752);

    dim3 gMerged(14, 79);   // BN=128, Nc=1792

    for (int l = 0; l < NLAYERS; ++l) {
        for (int s = 0; s < 2; ++s) {
            size_t ls = (size_t)(l * 2 + s);
            // xe | Q^T|K^T|V = x @ [We; Wqkv@We]^T  (one GEMM)
            gemm_lds<3, 128><<<gMerged, blk, 0, stream>>>(
                xbb, wMerged + ls * 458752, (float*)qkv, xeb, N_NODES, 256, 0, 0, 0, 0);
            edge_attn_csr<<<dim3(N_NODES / 4), blk, 0, stream>>>(csr_off, csr_src,
                                                                 qkv, attn_bf);
            if (s == 0) {
                fused_tail<false><<<dim3(625), blk, 0, stream>>>(
                    attn_bf, wO + ls * 131072, xbb, xeb, bo + ls * 256,
                    lng + (size_t)(l * 3) * 256, lnb + (size_t)(l * 3) * 256,
                    nullptr, nullptr, nullptr, nullptr,
                    nullptr, xbb, N_NODES);
            } else {
                bool lastL = (l == NLAYERS - 1);
                fused_tail<true><<<dim3(625), blk, 0, stream>>>(
                    attn_bf, wO + ls * 131072, xbb, xeb, bo + ls * 256,
                    lng + (size_t)(l * 3 + 1) * 256, lnb + (size_t)(l * 3 + 1) * 256,
                    wM + (size_t)l * 65536, mlpb + (size_t)l * 256,
                    lng + (size_t)(l * 3 + 2) * 256, lnb + (size_t)(l * 3 + 2) * 256,
                    lastL ? out : nullptr, xbb, N_NODES);
            }
        }
    }
}

// Round 15
// 643.508 us; speedup vs baseline: 1.3162x; 1.0088x over previous
//
#include <hip/hip_runtime.h>
#include <hip/hip_bf16.h>

#define N_NODES 10000
#define N_EDGES 40000
#define NLAYERS 5

typedef __bf16 bf16x8 __attribute__((ext_vector_type(8)));
typedef __bf16 bf16x4 __attribute__((ext_vector_type(4)));
typedef float  f32x4  __attribute__((ext_vector_type(4)));

__device__ __forceinline__ bf16x8 cvt8(float4 a, float4 b) {
    bf16x8 r;
    r[0] = (__bf16)a.x; r[1] = (__bf16)a.y; r[2] = (__bf16)a.z; r[3] = (__bf16)a.w;
    r[4] = (__bf16)b.x; r[5] = (__bf16)b.y; r[6] = (__bf16)b.z; r[7] = (__bf16)b.w;
    return r;
}

__device__ __forceinline__ void gload_lds16(const void* g, void* l) {
    __builtin_amdgcn_global_load_lds(
        (const __attribute__((address_space(1))) void*)g,
        (__attribute__((address_space(3))) void*)l, 16, 0, 0);
}

// T1: bijective XCD-aware block swizzle (m204). Pure relabeling — correctness-safe.
__device__ __forceinline__ int xcd_swz(int flat, int nwg) {
    int xcd = flat & 7;
    int idx = flat >> 3;
    int q = nwg >> 3, r = nwg & 7;
    return (xcd < r ? xcd * (q + 1) : r * (q + 1) + (xcd - r) * q) + idx;
}

// ---------------- all f32->bf16 weight/x conversions in ONE kernel ----------------
__global__ __launch_bounds__(256) void prep_cvt(
    const float* __restrict__ We, const float* __restrict__ Wq,
    const float* __restrict__ Wk, const float* __restrict__ Wv,
    const float* __restrict__ Wo, const float* __restrict__ mlpW,
    const float* __restrict__ x_in,
    __bf16* __restrict__ wMerged, __bf16* __restrict__ wQKVtmp,
    __bf16* __restrict__ wOd, __bf16* __restrict__ wMd, __bf16* __restrict__ xbb)
{
    const int reg = blockIdx.y;
    long i0 = (long)blockIdx.x * blockDim.x + threadIdx.x;
    long stride = (long)gridDim.x * blockDim.x;
    if (reg == 0) {                       // We -> wMerged rows 0..255 (stride 458752)
        for (long i = i0; i < 81920; i += stride) {
            long e = i * 8; long ch = e >> 16; long r = e & 65535;
            *(bf16x8*)(wMerged + ch * 458752 + r) =
                cvt8(*(const float4*)(We + e), *(const float4*)(We + e + 4));
        }
    } else if (reg == 1 || reg == 2) {    // Wq/Wk row-permuted
        const float* S = (reg == 1) ? Wq : Wk;
        __bf16* D = wQKVtmp + ((reg == 2) ? 131072 : 0);
        for (long i = i0; i < 163840; i += stride) {
            long e = i * 8;
            int slot = (int)(e >> 17); int rem = (int)(e & 131071);
            int row = rem >> 8; int col = rem & 255;
            int srow = ((row & 31) << 4) | (row >> 5);
            const float* sp = S + ((long)slot << 17) + ((long)srow << 8) + col;
            *(bf16x8*)(D + (long)slot * 393216 + ((long)row << 8) + col) =
                cvt8(*(const float4*)sp, *(const float4*)(sp + 4));
        }
    } else if (reg == 3) {                // Wv
        for (long i = i0; i < 163840; i += stride) {
            long e = i * 8; long ch = e >> 17; long r = e & 131071;
            *(bf16x8*)(wQKVtmp + 262144 + ch * 393216 + r) =
                cvt8(*(const float4*)(Wv + e), *(const float4*)(Wv + e + 4));
        }
    } else if (reg == 4) {                // Wo flat
        for (long i = i0; i < 163840; i += stride) {
            long e = i * 8;
            *(bf16x8*)(wOd + e) =
                cvt8(*(const float4*)(Wo + e), *(const float4*)(Wo + e + 4));
        }
    } else if (reg == 5) {                // mlpW flat
        for (long i = i0; i < 40960; i += stride) {
            long e = i * 8;
            *(bf16x8*)(wMd + e) =
                cvt8(*(const float4*)(mlpW + e), *(const float4*)(mlpW + e + 4));
        }
    } else {                              // x_in flat
        for (long i = i0; i < 320000; i += stride) {
            long e = i * 8;
            *(bf16x8*)(xbb + e) =
                cvt8(*(const float4*)(x_in + e), *(const float4*)(x_in + e + 4));
        }
    }
}

// WeT[slot][n][k] = We[slot][k][n], bf16. grid (16, 10).
__global__ __launch_bounds__(256) void transpose_we(
    const float* __restrict__ S, __bf16* __restrict__ D)
{
    __shared__ float tile[64][65];
    const int slot = blockIdx.y;
    const int tx = blockIdx.x & 3, ty = blockIdx.x >> 2;
    const float* sp = S + (size_t)slot * 65536 + (size_t)(ty * 64) * 256 + tx * 64;
    const int t = threadIdx.x;
    #pragma unroll
    for (int j = 0; j < 16; ++j) {
        int idx = t + 256 * j;
        int r = idx >> 6, c = idx & 63;
        tile[r][c] = sp[r * 256 + c];
    }
    __syncthreads();
    __bf16* dp = D + (size_t)slot * 65536 + (size_t)(tx * 64) * 256 + ty * 64;
    #pragma unroll
    for (int j = 0; j < 16; ++j) {
        int idx = t + 256 * j;
        int nl = idx >> 6, kl = idx & 63;
        dp[nl * 256 + kl] = (__bf16)tile[kl][nl];
    }
}

// ---------------- CSR build ----------------
__global__ __launch_bounds__(256) void hist_dst(
    const int* __restrict__ eidx, int* __restrict__ counts)
{
    int e = blockIdx.x * 256 + threadIdx.x;
    if (e < N_EDGES) atomicAdd(&counts[eidx[N_EDGES + e]], 1);
}

__global__ __launch_bounds__(256) void scan_offsets(
    const int* __restrict__ counts, int* __restrict__ offs,
    int* __restrict__ wrk, int n)
{
    const int tid = threadIdx.x;
    const int base = tid * 40;
    int local[40];
    int s = 0;
    #pragma unroll
    for (int j = 0; j < 40; ++j) {
        int i = base + j;
        int v = (i < n) ? counts[i] : 0;
        local[j] = s; s += v;
    }
    __shared__ int sm[256];
    sm[tid] = s;
    __syncthreads();
    for (int off = 1; off < 256; off <<= 1) {
        int t2 = (tid >= off) ? sm[tid - off] : 0;
        __syncthreads();
        sm[tid] += t2;
        __syncthreads();
    }
    int pre = (tid == 0) ? 0 : sm[tid - 1];
    #pragma unroll
    for (int j = 0; j < 40; ++j) {
        int i = base + j;
        if (i < n) { int v = pre + local[j]; offs[i] = v; wrk[i] = v; }
    }
    if (tid == 255) offs[n] = sm[255];
}

__global__ __launch_bounds__(256) void scatter_csr(
    const int* __restrict__ eidx, int* __restrict__ wrk, int* __restrict__ csr_src)
{
    int e = blockIdx.x * 256 + threadIdx.x;
    if (e < N_EDGES) {
        int sn = eidx[e];
        int d  = eidx[N_EDGES + e];
        int pos = atomicAdd(&wrk[d], 1);
        csr_src[pos] = sn;
    }
}

// ---------------- LDS-staged bf16 GEMM (merged x->xe|QKV + weight prep) ----------------
template<int MODE, int BN>
__global__ __launch_bounds__(256) void gemm_lds(
    const __bf16* __restrict__ A, const __bf16* __restrict__ W,
    float* __restrict__ Cf, __bf16* __restrict__ Ch,
    int M, int K, int ldc, long sA, long sW, long sC)
{
    __shared__ __bf16 As[128 * 64];
    __shared__ __bf16 Wsh[BN * 64];
    constexpr int NF = BN / 32;
    A += (long)blockIdx.z * sA;
    W += (long)blockIdx.z * sW;
    if (Ch) Ch += (long)blockIdx.z * sC;
    const int tid = threadIdx.x;
    const int ln  = tid & 63;
    const int wv  = tid >> 6;
    const int wr  = wv >> 1, wc = wv & 1;

    // T1 XCD swizzle of the (x,y) block coordinates (bijective, perf-only)
    const int nx = gridDim.x, nwg = nx * gridDim.y;
    const int swz = xcd_swz(blockIdx.y * nx + blockIdx.x, nwg);
    const int brow0 = (swz / nx) * 128;
    const int colb0 = (swz % nx) * BN;

    const int srow = ln >> 3;
    const int scol = ((ln & 7) ^ srow) * 8;
    const int fr = ln & 15;
    const int kq = ln >> 4;
    char* asb = (char*)As;
    char* wsb = (char*)Wsh;

    f32x4 acc[4][NF];
    #pragma unroll
    for (int m = 0; m < 4; ++m)
        #pragma unroll
        for (int n = 0; n < NF; ++n) acc[m][n] = (f32x4){0.f, 0.f, 0.f, 0.f};

    const int nt = K >> 6;
    for (int t = 0; t < nt; ++t) {
        const int kk0 = t << 6;
        if (t) __syncthreads();
        #pragma unroll
        for (int c = 0; c < 4; ++c) {
            int ch = wv * 4 + c;
            int grow = brow0 + ch * 8 + srow;
            if (grow >= M) grow = M - 1;
            gload_lds16(A + (size_t)grow * K + kk0 + scol, asb + ch * 1024);
        }
        #pragma unroll
        for (int c = 0; c < NF; ++c) {
            int ch = wv * NF + c;
            int grow = colb0 + ch * 8 + srow;
            gload_lds16(W + (size_t)grow * K + kk0 + scol, wsb + ch * 1024);
        }
        __syncthreads();
        #pragma unroll
        for (int ks = 0; ks < 2; ++ks) {
            const int kb = ks * 64 + kq * 16;
            const int sw = (fr & 7) << 4;
            bf16x8 af[4], wf[NF];
            #pragma unroll
            for (int m = 0; m < 4; ++m) {
                int row = wr * 64 + m * 16 + fr;
                af[m] = *(const bf16x8*)(asb + row * 128 + (kb ^ sw));
            }
            #pragma unroll
            for (int n = 0; n < NF; ++n) {
                int row = wc * (BN / 2) + n * 16 + fr;
                wf[n] = *(const bf16x8*)(wsb + row * 128 + (kb ^ sw));
            }
            #pragma unroll
            for (int m = 0; m < 4; ++m)
                #pragma unroll
                for (int n = 0; n < NF; ++n)
                    acc[m][n] = __builtin_amdgcn_mfma_f32_16x16x32_bf16(
                        af[m], wf[n], acc[m][n], 0, 0, 0);
        }
    }

    const int rq = (ln >> 4) * 4;
    #pragma unroll
    for (int m = 0; m < 4; ++m) {
        #pragma unroll
        for (int rr = 0; rr < 4; ++rr) {
            int orow = brow0 + wr * 64 + m * 16 + rq + rr;
            if (orow < M) {
                #pragma unroll
                for (int n = 0; n < NF; ++n) {
                    int c = colb0 + wc * (BN / 2) + fr + n * 16;
                    if (MODE == 0)      Cf[(size_t)orow * ldc + c] = acc[m][n][rr];
                    else if (MODE == 1) Ch[(size_t)orow * ldc + c] = (__bf16)acc[m][n][rr];
                    else {
                        if (c < 256) Ch[(size_t)orow * 256 + c] = (__bf16)acc[m][n][rr];
                        else ((__bf16*)Cf)[(size_t)orow * 1536 + (c - 256)] = (__bf16)acc[m][n][rr];
                    }
                }
            }
        }
    }
}

// ---------------- per-dst attention via MFMA, one wave per node ----------------
// qkv per node (1536 bf16): Q^T[16a][32h] | K^T[16a][32h] | V[32h][16b].
__global__ __launch_bounds__(256) void edge_attn_csr(
    const int* __restrict__ csr_off, const int* __restrict__ csr_src,
    const __bf16* __restrict__ qkv, __bf16* __restrict__ attn_bf)
{
    const int lane = threadIdx.x & 63;
    const int blk = xcd_swz(blockIdx.x, gridDim.x);   // T1: contiguous nodes/XCD
    const int d = blk * 4 + (threadIdx.x >> 6);
    const int fr = lane & 15;
    const int G  = lane >> 4;

    const __bf16* qT = qkv + (size_t)d * 1536;
    const bf16x8 qf = *(const bf16x8*)(qT + fr * 32 + G * 8);

    const f32x4 zero = {0.f, 0.f, 0.f, 0.f};
    f32x4 acc0 = zero, acc1 = zero;

    const int i0 = csr_off[d], i1 = csr_off[d + 1];
    int sN = (i0 < i1) ? csr_src[i0] : 0;
    bf16x8 kfN = *(const bf16x8*)(qkv + (size_t)sN * 1536 + 512 + fr * 32 + G * 8);
    for (int i = i0; i < i1; ++i) {
        const int s = sN;
        const bf16x8 kf = kfN;
        if (i + 1 < i1) {
            sN = csr_src[i + 1];
            kfN = *(const bf16x8*)(qkv + (size_t)sN * 1536 + 512 + fr * 32 + G * 8);
        }
        const __bf16* vp = qkv + (size_t)s * 1536 + 1024;
        bf16x8 vf0 = {0, 0, 0, 0, 0, 0, 0, 0};
        bf16x8 vf1 = {0, 0, 0, 0, 0, 0, 0, 0};
        if (G < 2) {
            vf0 = *(const bf16x8*)(vp + fr * 16 + G * 8);
            vf1 = *(const bf16x8*)(vp + (16 + fr) * 16 + G * 8);
        }
        f32x4 al = __builtin_amdgcn_mfma_f32_16x16x32_bf16(kf, qf, zero, 0, 0, 0);

        float mx = fmaxf(fmaxf(al[0], al[1]), fmaxf(al[2], al[3]));
        mx = fmaxf(mx, __shfl_xor(mx, 16));
        mx = fmaxf(mx, __shfl_xor(mx, 32));
        float p[4];
        #pragma unroll
        for (int r = 0; r < 4; ++r) p[r] = __expf((al[r] - mx) * 0.25f);
        float sum = p[0] + p[1] + p[2] + p[3];
        sum += __shfl_xor(sum, 16);
        sum += __shfl_xor(sum, 32);
        const float inv = 1.f / sum;

        bf16x8 paf;
        #pragma unroll
        for (int j = 0; j < 8; ++j) {
            int srcLane = fr + ((G * 8 + j) >> 2) * 16;
            float v = __shfl(p[j & 3], srcLane);
            paf[j] = (G < 2) ? (__bf16)(v * inv) : (__bf16)0.f;
        }

        acc0 = __builtin_amdgcn_mfma_f32_16x16x32_bf16(paf, vf0, acc0, 0, 0, 0);
        acc1 = __builtin_amdgcn_mfma_f32_16x16x32_bf16(paf, vf1, acc1, 0, 0, 0);
    }

    __bf16* ob = attn_bf + (size_t)d * 512;
    bf16x4 o0, o1;
    #pragma unroll
    for (int r = 0; r < 4; ++r) { o0[r] = (__bf16)acc0[r]; o1[r] = (__bf16)acc1[r]; }
    *(bf16x4*)(ob + fr * 16 + G * 4)       = o0;
    *(bf16x4*)(ob + 256 + fr * 16 + G * 4) = o1;
}

// ---------------- fused Wo-GEMM + residual + LN (+ optional chained MLP+LN) ----------------
// Phase 1: P = attn[Mx512] @ Wo[256x512]^T; x1 = LN(xres + P + xe + bo).
// CHAIN: keep x1 in LDS, x2 = LN(x1 + x1@Wm^T + mb); write x2 (round-14 path).
// !CHAIN: NEW coalesced epilogue — frag accs -> padded Pld -> thread=(row,16 cols)
// coalesced residual reads + shfl-LN + contiguous bf16x8 stores.
// BM=16 (grid 625, T1-swizzled), 256 threads.
template<bool CHAIN>
__global__ __launch_bounds__(256) void fused_tail(
    const __bf16* __restrict__ A, const __bf16* __restrict__ W,
    const __bf16* __restrict__ xres, const __bf16* __restrict__ tb,
    const float* __restrict__ bias, const float* __restrict__ g1,
    const float* __restrict__ b1,
    const __bf16* __restrict__ Wm, const float* __restrict__ mb,
    const float* __restrict__ g2, const float* __restrict__ b2,
    float* __restrict__ outf, __bf16* __restrict__ outb, int M)
{
    __shared__ __bf16 As[16 * 64];                 // 2 KB
    __shared__ __bf16 Wsh[256 * 64];               // 32 KB (Wo tiles, reused for Wm)
    __shared__ __bf16 X1[CHAIN ? 16 * 256 : 2];    // 8 KB swizzled x1 tile
    __shared__ float  Pld[CHAIN ? 1 : 16][CHAIN ? 4 : 260];  // coalesce buffer (!CHAIN)
    __shared__ float sm_s[4][16];
    __shared__ float sm_q[4][16];
    const int tid = threadIdx.x;
    const int ln  = tid & 63;
    const int wv  = tid >> 6;
    const int fr  = ln & 15;
    const int kq  = ln >> 4;
    const int brow0 = xcd_swz(blockIdx.x, gridDim.x) * 16;   // T1 relabel
    const int srow = ln >> 3;
    const int scol = ((ln & 7) ^ srow) * 8;
    char* asb = (char*)As;
    char* wsb = (char*)Wsh;
    char* x1b = (char*)X1;
    const f32x4 zero = {0.f, 0.f, 0.f, 0.f};

    f32x4 acc[4];
    #pragma unroll
    for (int n = 0; n < 4; ++n) acc[n] = zero;

    // ---- phase 1: K=512 GEMM, A+W staged per tile ----
    for (int t = 0; t < 8; ++t) {
        const int kk0 = t << 6;
        if (t) __syncthreads();
        if (wv < 2) {
            int grow = brow0 + wv * 8 + srow;
            if (grow >= M) grow = M - 1;
            gload_lds16(A + (size_t)grow * 512 + kk0 + scol, asb + wv * 1024);
        }
        #pragma unroll
        for (int c = 0; c < 8; ++c) {
            int ch = wv * 8 + c;
            gload_lds16(W + (size_t)(ch * 8 + srow) * 512 + kk0 + scol, wsb + ch * 1024);
        }
        __syncthreads();
        #pragma unroll
        for (int ks = 0; ks < 2; ++ks) {
            const int kb = ks * 64 + kq * 16;
            const int sw = (fr & 7) << 4;
            bf16x8 af = *(const bf16x8*)(asb + fr * 128 + (kb ^ sw));
            #pragma unroll
            for (int n = 0; n < 4; ++n) {
                bf16x8 wf = *(const bf16x8*)(wsb + (wv * 64 + n * 16 + fr) * 128 + (kb ^ sw));
                acc[n] = __builtin_amdgcn_mfma_f32_16x16x32_bf16(af, wf, acc[n], 0, 0, 0);
            }
        }
    }

    if (!CHAIN) {
        // ---- NEW coalesced epilogue ----
        // fragment scatter into padded LDS (2-way-max bank pattern)
        #pragma unroll
        for (int n = 0; n < 4; ++n)
            #pragma unroll
            for (int rr = 0; rr < 4; ++rr)
                Pld[kq * 4 + rr][wv * 64 + n * 16 + fr] = acc[n][rr];
        __syncthreads();

        const int row = tid >> 4;          // 0..15
        const int c0  = (tid & 15) * 16;   // 0..240
        const int gr  = brow0 + row;       // 625*16 == M, always valid

        float v[16];
        #pragma unroll
        for (int j = 0; j < 16; j += 4) {
            f32x4 pp = *(const f32x4*)&Pld[row][c0 + j];
            v[j] = pp[0]; v[j + 1] = pp[1]; v[j + 2] = pp[2]; v[j + 3] = pp[3];
        }
        bf16x8 xr0 = *(const bf16x8*)(xres + (size_t)gr * 256 + c0);
        bf16x8 xr1 = *(const bf16x8*)(xres + (size_t)gr * 256 + c0 + 8);
        bf16x8 tv0 = *(const bf16x8*)(tb   + (size_t)gr * 256 + c0);
        bf16x8 tv1 = *(const bf16x8*)(tb   + (size_t)gr * 256 + c0 + 8);
        #pragma unroll
        for (int j = 0; j < 8; ++j) {
            v[j]     += (float)xr0[j] + (float)tv0[j] + bias[c0 + j];
            v[8 + j] += (float)xr1[j] + (float)tv1[j] + bias[c0 + 8 + j];
        }
        float s = 0.f, q = 0.f;
        #pragma unroll
        for (int j = 0; j < 16; ++j) { s += v[j]; q += v[j] * v[j]; }
        #pragma unroll
        for (int mask = 1; mask < 16; mask <<= 1) {
            s += __shfl_xor(s, mask);
            q += __shfl_xor(q, mask);
        }
        float mean = s * (1.f / 256.f);
        float invs = rsqrtf(q * (1.f / 256.f) - mean * mean + 1e-5f);

        bf16x8 ob0, ob1;
        #pragma unroll
        for (int j = 0; j < 8; ++j) {
            float o0 = (v[j]     - mean) * invs * g1[c0 + j]     + b1[c0 + j];
            float o1 = (v[8 + j] - mean) * invs * g1[c0 + 8 + j] + b1[c0 + 8 + j];
            ob0[j] = (__bf16)o0;
            ob1[j] = (__bf16)o1;
        }
        *(bf16x8*)(outb + (size_t)gr * 256 + c0)     = ob0;
        *(bf16x8*)(outb + (size_t)gr * 256 + c0 + 8) = ob1;
        return;
    }

    // ---- CHAIN path: proven round-14 epilogue, unchanged ----
    float s2[4] = {0.f, 0.f, 0.f, 0.f}, q2[4] = {0.f, 0.f, 0.f, 0.f};
    #pragma unroll
    for (int n = 0; n < 4; ++n) {
        const int col = wv * 64 + n * 16 + fr;
        const float bi = bias[col];
        #pragma unroll
        for (int rr = 0; rr < 4; ++rr) {
            int gr = brow0 + kq * 4 + rr; if (gr >= M) gr = M - 1;
            float v = acc[n][rr] + (float)xres[(size_t)gr * 256 + col]
                      + (float)tb[(size_t)gr * 256 + col] + bi;
            acc[n][rr] = v;
            s2[rr] += v; q2[rr] += v * v;
        }
    }
    #pragma unroll
    for (int mask = 1; mask < 16; mask <<= 1)
        #pragma unroll
        for (int rr = 0; rr < 4; ++rr) {
            s2[rr] += __shfl_xor(s2[rr], mask);
            q2[rr] += __shfl_xor(q2[rr], mask);
        }
    if (fr == 0) {
        #pragma unroll
        for (int rr = 0; rr < 4; ++rr) {
            sm_s[wv][kq * 4 + rr] = s2[rr];
            sm_q[wv][kq * 4 + rr] = q2[rr];
        }
    }
    __syncthreads();
    float mean[4], invs[4];
    #pragma unroll
    for (int rr = 0; rr < 4; ++rr) {
        int rw = kq * 4 + rr;
        float ts = sm_s[0][rw] + sm_s[1][rw] + sm_s[2][rw] + sm_s[3][rw];
        float tq = sm_q[0][rw] + sm_q[1][rw] + sm_q[2][rw] + sm_q[3][rw];
        float mn = ts * (1.f / 256.f);
        mean[rr] = mn;
        invs[rr] = rsqrtf(tq * (1.f / 256.f) - mn * mn + 1e-5f);
    }

    // x1 -> LDS (swizzled), x2 = LN(x1 + x1@Wm^T + mb)
    #pragma unroll
    for (int n = 0; n < 4; ++n) {
        const int col = wv * 64 + n * 16 + fr;
        const float gv = g1[col], bv = b1[col];
        #pragma unroll
        for (int rr = 0; rr < 4; ++rr) {
            int row = kq * 4 + rr;
            float o = (acc[n][rr] - mean[rr]) * invs[rr] * gv + bv;
            *(__bf16*)(x1b + row * 512 + ((col * 2) ^ ((row & 7) << 4))) = (__bf16)o;
        }
    }
    __syncthreads();

    f32x4 acc2[4];
    #pragma unroll
    for (int n = 0; n < 4; ++n) acc2[n] = zero;

    for (int t = 0; t < 4; ++t) {
        if (t) __syncthreads();
        #pragma unroll
        for (int c = 0; c < 8; ++c) {
            int ch = wv * 8 + c;
            gload_lds16(Wm + (size_t)(ch * 8 + srow) * 256 + t * 64 + scol, wsb + ch * 1024);
        }
        __syncthreads();
        #pragma unroll
        for (int ks = 0; ks < 2; ++ks) {
            const int kb = t * 128 + ks * 64 + kq * 16;
            const int sw = (fr & 7) << 4;
            bf16x8 af = *(const bf16x8*)(x1b + fr * 512 + (kb ^ sw));
            const int kbl = ks * 64 + kq * 16;
            #pragma unroll
            for (int n = 0; n < 4; ++n) {
                bf16x8 wf = *(const bf16x8*)(wsb + (wv * 64 + n * 16 + fr) * 128 + (kbl ^ sw));
                acc2[n] = __builtin_amdgcn_mfma_f32_16x16x32_bf16(af, wf, acc2[n], 0, 0, 0);
            }
        }
    }

    float s3[4] = {0.f, 0.f, 0.f, 0.f}, q3[4] = {0.f, 0.f, 0.f, 0.f};
    #pragma unroll
    for (int n = 0; n < 4; ++n) {
        const int col = wv * 64 + n * 16 + fr;
        const float bi = mb[col];
        #pragma unroll
        for (int rr = 0; rr < 4; ++rr) {
            int row = kq * 4 + rr;
            float x1v = (float)*(const __bf16*)(x1b + row * 512 + ((col * 2) ^ ((row & 7) << 4)));
            float v = acc2[n][rr] + x1v + bi;
            acc2[n][rr] = v;
            s3[rr] += v; q3[rr] += v * v;
        }
    }
    #pragma unroll
    for (int mask = 1; mask < 16; mask <<= 1)
        #pragma unroll
        for (int rr = 0; rr < 4; ++rr) {
            s3[rr] += __shfl_xor(s3[rr], mask);
            q3[rr] += __shfl_xor(q3[rr], mask);
        }
    __syncthreads();   // all LN1 sm reads done before overwrite
    if (fr == 0) {
        #pragma unroll
        for (int rr = 0; rr < 4; ++rr) {
            sm_s[wv][kq * 4 + rr] = s3[rr];
            sm_q[wv][kq * 4 + rr] = q3[rr];
        }
    }
    __syncthreads();
    #pragma unroll
    for (int rr = 0; rr < 4; ++rr) {
        int rw = kq * 4 + rr;
        float ts = sm_s[0][rw] + sm_s[1][rw] + sm_s[2][rw] + sm_s[3][rw];
        float tq = sm_q[0][rw] + sm_q[1][rw] + sm_q[2][rw] + sm_q[3][rw];
        float mn = ts * (1.f / 256.f);
        mean[rr] = mn;
        invs[rr] = rsqrtf(tq * (1.f / 256.f) - mn * mn + 1e-5f);
    }
    #pragma unroll
    for (int n = 0; n < 4; ++n) {
        const int col = wv * 64 + n * 16 + fr;
        const float gv = g2[col], bv = b2[col];
        #pragma unroll
        for (int rr = 0; rr < 4; ++rr) {
            int gr = brow0 + kq * 4 + rr;
            if (gr < M) {
                float o = (acc2[n][rr] - mean[rr]) * invs[rr] * gv + bv;
                outb[(size_t)gr * 256 + col] = (__bf16)o;
                if (outf) outf[(size_t)gr * 256 + col] = o;
            }
        }
    }
}

extern "C" void kernel_launch(void* const* d_in, const int* in_sizes, int n_in,
                              void* d_out, int out_size, void* d_ws, size_t ws_size,
                              hipStream_t stream)
{
    const int*   eidx = (const int*)  d_in[0];
    const float* x_in = (const float*)d_in[1];
    const float* We   = (const float*)d_in[2];
    const float* Wq   = (const float*)d_in[3];
    const float* Wk   = (const float*)d_in[4];
    const float* Wv   = (const float*)d_in[5];
    const float* Wo   = (const float*)d_in[6];
    const float* bo   = (const float*)d_in[7];
    const float* lng  = (const float*)d_in[8];
    const float* lnb  = (const float*)d_in[9];
    const float* mlpW = (const float*)d_in[10];
    const float* mlpb = (const float*)d_in[11];
    float* out = (float*)d_out;

    char* p = (char*)d_ws;
    __bf16* wMerged = (__bf16*)p; p += (size_t)10 * 458752 * 2;  // [10][1792][256]
    __bf16* wQKVtmp = (__bf16*)p; p += (size_t)10 * 393216 * 2;
    __bf16* wET     = (__bf16*)p; p += (size_t)10 * 65536  * 2;
    __bf16* wO      = (__bf16*)p; p += (size_t)10 * 131072 * 2;
    __bf16* wM      = (__bf16*)p; p += (size_t)5  * 65536  * 2;
    __bf16* qkv     = (__bf16*)p; p += (size_t)N_NODES * 1536 * 2;
    __bf16* attn_bf = (__bf16*)p; p += (size_t)N_NODES * 512 * 2;
    __bf16* xeb     = (__bf16*)p; p += (size_t)N_NODES * 256 * 2;
    __bf16* xbb     = (__bf16*)p; p += (size_t)N_NODES * 256 * 2;
    int* counts  = (int*)p;    p += (size_t)(N_NODES + 16) * 4;
    int* csr_off = (int*)p;    p += (size_t)(N_NODES + 16) * 4;
    int* csr_wrk = (int*)p;    p += (size_t)(N_NODES + 16) * 4;
    int* csr_src = (int*)p;    p += (size_t)N_EDGES * 4;
    if ((size_t)(p - (char*)d_ws) > ws_size) return;

    dim3 blk(256);

    // ---- prep: CSR + weight conversion ----
    hipMemsetAsync(counts, 0, (size_t)(N_NODES + 16) * 4, stream);
    hist_dst<<<dim3(157), blk, 0, stream>>>(eidx, counts);
    scan_offsets<<<dim3(1), blk, 0, stream>>>(counts, csr_off, csr_wrk, N_NODES);
    scatter_csr<<<dim3(157), blk, 0, stream>>>(eidx, csr_wrk, csr_src);

    prep_cvt<<<dim3(128, 7), blk, 0, stream>>>(We, Wq, Wk, Wv, Wo, mlpW, x_in,
                                               wMerged, wQKVtmp, wO, wM, xbb);
    transpose_we<<<dim3(16, 10), blk, 0, stream>>>(We, wET);

    // W'[l] = Wqkv_perm[l] @ We[l] -> wMerged rows 256..1791 (batched)
    gemm_lds<1, 64><<<dim3(4, 12, 10), blk, 0, stream>>>(
        wQKVtmp, wET, nullptr, wMerged + 65536, 1536, 256, 256,
        393216, 65536, 458752);

    dim3 gMerged(14, 79);   // BN=128, Nc=1792

    for (int l = 0; l < NLAYERS; ++l) {
        for (int s = 0; s < 2; ++s) {
            size_t ls = (size_t)(l * 2 + s);
            // xe | Q^T|K^T|V = x @ [We; Wqkv@We]^T  (one GEMM)
            gemm_lds<3, 128><<<gMerged, blk, 0, stream>>>(
                xbb, wMerged + ls * 458752, (float*)qkv, xeb, N_NODES, 256, 0, 0, 0, 0);
            edge_attn_csr<<<dim3(N_NODES / 4), blk, 0, stream>>>(csr_off, csr_src,
                                                                 qkv, attn_bf);
            if (s == 0) {
                fused_tail<false><<<dim3(625), blk, 0, stream>>>(
                    attn_bf, wO + ls * 131072, xbb, xeb, bo + ls * 256,
                    lng + (size_t)(l * 3) * 256, lnb + (size_t)(l * 3) * 256,
                    nullptr, nullptr, nullptr, nullptr,
                    nullptr, xbb, N_NODES);
            } else {
                bool lastL = (l == NLAYERS - 1);
                fused_tail<true><<<dim3(625), blk, 0, stream>>>(
                    attn_bf, wO + ls * 131072, xbb, xeb, bo + ls * 256,
                    lng + (size_t)(l * 3 + 1) * 256, lnb + (size_t)(l * 3 + 1) * 256,
                    wM + (size_t)l * 65536, mlpb + (size_t)l * 256,
                    lng + (size_t)(l * 3 + 2) * 256, lnb + (size_t)(l * 3 + 2) * 256,
                    lastL ? out : nullptr, xbb, N_NODES);
            }
        }
    }
}